// Round 1
// baseline (2821.945 us; speedup 1.0000x reference)
//
#include <hip/hip_runtime.h>

// ---------------- problem dims ----------------
constexpr int NB = 16;    // batch
constexpr int CC = 32;    // in channels
constexpr int VV = 2048;  // fine nodes
constexpr int VCC = 256;  // coarse nodes
constexpr int SS = 64;    // super nodes
constexpr int LL = 12;    // time
constexpr int CO = 32;    // out channels
constexpr long MM = (long)NB * CO * LL;  // 6144 rows in node-last layout

// =====================================================================
// K1: x [nc, V, 12] -> xt [nc, 12, V]
__global__ __launch_bounds__(256)
void transpose_vl(const float* __restrict__ in, float* __restrict__ out) {
    __shared__ float t[128 * 12];
    const long nc = blockIdx.y;
    const int v0 = blockIdx.x * 128;
    const float* src = in + (nc * VV + v0) * 12;
    for (int f = threadIdx.x; f < 128 * 12; f += 256) t[f] = src[f];
    __syncthreads();
    float* dst = out + nc * 12L * VV;
    for (int g = threadIdx.x; g < 128 * 12; g += 256) {
        int l = g >> 7, vv = g & 127;
        dst[(long)l * VV + v0 + vv] = t[vv * 12 + l];
    }
}

// K17: in [nc, 12, Kn] -> out [nc, Kn, 12]   (TW = tile width over Kn)
__global__ __launch_bounds__(256)
void transpose_lv(const float* __restrict__ in, float* __restrict__ out, int Kn, int TW) {
    __shared__ float t[128 * 12];
    const long nc = blockIdx.y;
    const int v0 = blockIdx.x * TW;
    const float* src = in + nc * 12L * Kn;
    for (int g = threadIdx.x; g < TW * 12; g += 256) {
        int l = g / TW, vv = g - l * TW;
        t[vv * 12 + l] = src[(long)l * Kn + v0 + vv];
    }
    __syncthreads();
    float* dst = out + (nc * Kn + v0) * 12L;
    for (int f = threadIdx.x; f < TW * 12; f += 256) dst[f] = t[f];
}

// small dense transpose: in [rows, cols] -> out [cols, rows]
__global__ __launch_bounds__(256)
void transpose2d(const float* __restrict__ in, float* __restrict__ out, int rows, int cols) {
    __shared__ float t[32][33];
    const int r0 = blockIdx.y * 32, c0 = blockIdx.x * 32;
    const int ty = threadIdx.x / 32, tx = threadIdx.x % 32;
    for (int i = ty; i < 32; i += 8) t[i][tx] = in[(long)(r0 + i) * cols + c0 + tx];
    __syncthreads();
    for (int i = ty; i < 32; i += 8) out[(long)(c0 + i) * rows + r0 + tx] = t[tx][i];
}

// =====================================================================
// channel mix: in [16, 32, R] node-last, W [32,96].
// writes (optionally) j=0 -> o0 [M, Kn]; j=j1 -> o1 at (ld1, col co1);
// if DO2: j=2 -> o1 at col co1+Kn (interleaved [M, 2*Kn]).
template <bool DO0, bool DO2>
__global__ __launch_bounds__(256)
void chanmix_k(const float* __restrict__ in, const float* __restrict__ Wt,
               int R, int Kn, float* __restrict__ o0,
               float* __restrict__ o1, int ld1, int co1, int j1) {
    __shared__ float Ws[CO * 96];
    for (int idx = threadIdx.x; idx < CO * 96; idx += 256) Ws[idx] = Wt[idx];
    __syncthreads();
    const int nb = blockIdx.y;
    const int r = blockIdx.x * 256 + threadIdx.x;
    if (r >= R) return;
    const int l = r / Kn, k = r - l * Kn;
    float xv[CC];
#pragma unroll
    for (int c = 0; c < CC; ++c) xv[c] = in[((long)(nb * CC + c)) * R + r];
    for (int o = 0; o < CO; ++o) {
        float a0 = 0.f, a1 = 0.f, a2 = 0.f;
#pragma unroll
        for (int c = 0; c < CC; ++c) {
            const float x = xv[c];
            if (DO0) a0 = fmaf(Ws[o * 96 + c], x, a0);
            a1 = fmaf(Ws[o * 96 + j1 * 32 + c], x, a1);
            if (DO2) a2 = fmaf(Ws[o * 96 + 64 + c], x, a2);
        }
        const long mrow = (long)(nb * CO + o) * LL + l;
        if (DO0) o0[mrow * Kn + k] = a0;
        o1[mrow * ld1 + co1 + k] = a1;
        if (DO2) o1[mrow * ld1 + co1 + Kn + k] = a2;
    }
}

// =====================================================================
// generic fp32 GEMM: Out[m,n] = (ADDC0? C0[m,n]:0) + alpha*(RELU? relu(prod):prod)
//                               + (BIAS? bias[(m/12)&31]:0)
// X [M,K] row-major ldx, B [K,Nn] row-major ldb. M % BM == 0, Nn % BN == 0, K % BK == 0.
template <int BM, int BN, int BK, int TM, int TN, bool RELU, bool ADDC0, bool BIAS>
__global__ __launch_bounds__(256)
void gemm_k(const float* __restrict__ X, int ldx,
            const float* __restrict__ Bm, int ldb,
            const float* __restrict__ C0, int ldc,
            const float* __restrict__ bias,
            float* __restrict__ Out, int ldo, int K, float alpha) {
    constexpr int TX = BN / TN;            // threads along n
    constexpr int LX = (BM * BK) / 256;    // floats/thread X tile (4 or 2)
    constexpr int LB = (BN * BK) / 256;    // floats/thread B tile (4 or 2)
    __shared__ float Xs[BK][BM + 4];
    __shared__ float Bs[BK][BN + 4];
    const int tid = threadIdx.x;
    const int tx = tid % TX, ty = tid / TX;
    const long m0 = (long)blockIdx.y * BM;
    const int n0 = blockIdx.x * BN;
    const int xr = tid / (BK / LX);
    const int xcc = (tid % (BK / LX)) * LX;
    const int br = tid / (BN / LB);
    const int bc = (tid % (BN / LB)) * LB;

    float acc[TM][TN];
#pragma unroll
    for (int i = 0; i < TM; ++i)
#pragma unroll
        for (int j = 0; j < TN; ++j) acc[i][j] = 0.f;

    const float* Xp = X + (m0 + xr) * (long)ldx + xcc;
    const float* Bp = Bm + (long)br * ldb + n0 + bc;

    for (int k0 = 0; k0 < K; k0 += BK) {
        if constexpr (LX == 4) {
            const float4 v = *(const float4*)Xp;
            Xs[xcc + 0][xr] = v.x; Xs[xcc + 1][xr] = v.y;
            Xs[xcc + 2][xr] = v.z; Xs[xcc + 3][xr] = v.w;
        } else {
            const float2 v = *(const float2*)Xp;
            Xs[xcc + 0][xr] = v.x; Xs[xcc + 1][xr] = v.y;
        }
        if constexpr (LB == 4) {
            *(float4*)&Bs[br][bc] = *(const float4*)Bp;
        } else {
            *(float2*)&Bs[br][bc] = *(const float2*)Bp;
        }
        __syncthreads();
#pragma unroll
        for (int kk = 0; kk < BK; ++kk) {
            float a[TM], b[TN];
#pragma unroll
            for (int i = 0; i < TM; ++i) a[i] = Xs[kk][ty * TM + i];
#pragma unroll
            for (int j = 0; j < TN; ++j) b[j] = Bs[kk][tx * TN + j];
#pragma unroll
            for (int i = 0; i < TM; ++i)
#pragma unroll
                for (int j = 0; j < TN; ++j) acc[i][j] = fmaf(a[i], b[j], acc[i][j]);
        }
        __syncthreads();
        Xp += BK;
        Bp += (long)BK * ldb;
    }

#pragma unroll
    for (int i = 0; i < TM; ++i) {
        const long m = m0 + (long)ty * TM + i;
        float bv = 0.f;
        if (BIAS) bv = bias[(int)((m / LL) & (CO - 1))];
        const long obase = m * (long)ldo + n0 + tx * TN;
        long cbase = 0;
        if constexpr (ADDC0) cbase = m * (long)ldc + n0 + tx * TN;
#pragma unroll
        for (int j = 0; j < TN; ++j) {
            float p = acc[i][j];
            if (RELU) p = fmaxf(p, 0.f);
            p *= alpha;
            float c = 0.f;
            if constexpr (ADDC0) c = C0[cbase + j];
            Out[obase + j] = c + p + bv;
        }
    }
}

// =====================================================================
// as_mat[s,t] = relu( sum_i sxg[rowA(i)*64+s]*sxg[rowB(i)*64+t] - 0.5 )
// rowA: i flattened (c,n,l); rowB: i flattened (l,n,c)  [faithful mismatched orders]
__global__ __launch_bounds__(64)
void asmat_k(const float* __restrict__ sxg, float* __restrict__ am) {
    const int s = blockIdx.x, t = threadIdx.x;
    float acc = 0.f;
    for (int i = 0; i < 6144; ++i) {
        const int c = i / 192;
        const int rem = i - c * 192;
        const int n = rem / 12;
        const int l = rem - n * 12;
        const int rowA = (n * 32 + c) * 12 + l;
        const int l2 = i >> 9;
        const int rem2 = i & 511;
        const int n2 = rem2 >> 5;
        const int c2 = rem2 & 31;
        const int rowB = (n2 * 32 + c2) * 12 + l2;
        acc = fmaf(sxg[rowA * 64 + s], sxg[rowB * 64 + t], acc);
    }
    const float v = acc - 0.5f;
    am[s * 64 + t] = v > 0.f ? v : 0.f;
}

// sup[0] = softmax(rownorm(am)), sup[1] = softmax(rownorm(am^T))  (each row-wise)
__global__ __launch_bounds__(64)
void supbuild_k(const float* __restrict__ am, float* __restrict__ sup) {
    __shared__ float a[64][65];
    for (int idx = threadIdx.x; idx < 4096; idx += 64) a[idx >> 6][idx & 63] = am[idx];
    __syncthreads();
    const int r = threadIdx.x;
    // rows -> sup0
    {
        float rs = 0.f;
        for (int j = 0; j < 64; ++j) rs += a[r][j];
        const float dinv = rs > 0.f ? 1.f / rs : 0.f;
        float mx = -1e30f;
        for (int j = 0; j < 64; ++j) mx = fmaxf(mx, a[r][j] * dinv);
        float se = 0.f;
        for (int j = 0; j < 64; ++j) se += expf(a[r][j] * dinv - mx);
        const float inv = 1.f / se;
        for (int j = 0; j < 64; ++j) sup[r * 64 + j] = expf(a[r][j] * dinv - mx) * inv;
    }
    // cols (rows of am^T) -> sup1
    {
        float rs = 0.f;
        for (int j = 0; j < 64; ++j) rs += a[j][r];
        const float dinv = rs > 0.f ? 1.f / rs : 0.f;
        float mx = -1e30f;
        for (int j = 0; j < 64; ++j) mx = fmaxf(mx, a[j][r] * dinv);
        float se = 0.f;
        for (int j = 0; j < 64; ++j) se += expf(a[j][r] * dinv - mx);
        const float inv = 1.f / se;
        for (int j = 0; j < 64; ++j) sup[4096 + r * 64 + j] = expf(a[j][r] * dinv - mx) * inv;
    }
}

// =====================================================================
extern "C" void kernel_launch(void* const* d_in, const int* in_sizes, int n_in,
                              void* d_out, int out_size, void* d_ws, size_t ws_size,
                              hipStream_t stream) {
    (void)in_sizes; (void)n_in; (void)out_size; (void)ws_size;
    const float* x    = (const float*)d_in[0];
    const float* sup  = (const float*)d_in[1];  // [2, V, V]
    const float* supc = (const float*)d_in[2];  // [2, VC, VC]
    const float* acs  = (const float*)d_in[3];  // [VC, S]
    const float* afc  = (const float*)d_in[4];  // [V, VC]
    const float* W    = (const float*)d_in[5];  // [32, 96]
    const float* b    = (const float*)d_in[6];  // [32]
    float* ws = (float*)d_ws;

    // workspace layout (floats); small region aliases ybuf (dead after K3b)
    float* xt   = ws;                   // 12,582,912  [nc,12,V]
    float* hf   = ws + 12582912L;       // 12,582,912  y0 then hf (in-place)
    float* ybuf = ws + 25165824L;       // 12,582,912  y1 then y2
    float* xc   = ws + 25165824L;       // 1,572,864
    float* sxg  = ws + 26738688L;       //   393,216
    float* yc0  = ws + 27131904L;       // 1,572,864
    float* yc12 = ws + 28704768L;       // 3,145,728
    float* ys0  = ws + 31850496L;       //   393,216
    float* ys12 = ws + 32243712L;       //   786,432
    float* hc   = ws + 33030144L;       // 1,572,864
    float* hs   = ws + 34603008L;       //   393,216
    float* am   = ws + 34996224L;       //     4,096
    float* sups = ws + 35000320L;       //     8,192
    float* acsT = ws + 35008512L;       //    16,384
    float* afcT = ws + 35024896L;       //   524,288   (total 151 MB incl. ybuf)

    float* hf_out = (float*)d_out;
    float* hc_out = hf_out + 12582912L;
    float* hs_out = hf_out + 14155776L;

    // K1: xt = transpose(x)
    transpose_vl<<<dim3(VV / 128, NB * CC), 256, 0, stream>>>(x, xt);
    // K2a: y0 -> hf, y1 -> ybuf
    chanmix_k<true, false><<<dim3(96, 16), 256, 0, stream>>>(xt, W, LL * VV, VV, hf, ybuf, VV, 0, 1);
    // K3a: hf = y0 + y1@A1 + bias
    gemm_k<128, 128, 8, 8, 8, false, true, true><<<dim3(VV / 128, MM / 128), 256, 0, stream>>>(
        ybuf, VV, sup, VV, hf, VV, b, hf, VV, VV, 1.0f);
    // K2b: y2 -> ybuf
    chanmix_k<false, false><<<dim3(96, 16), 256, 0, stream>>>(xt, W, LL * VV, VV, nullptr, ybuf, VV, 0, 2);
    // K3b: hf += y2@A2
    gemm_k<128, 128, 8, 8, 8, false, true, false><<<dim3(VV / 128, MM / 128), 256, 0, stream>>>(
        ybuf, VV, sup + (long)VV * VV, VV, hf, VV, nullptr, hf, VV, VV, 1.0f);
    // K4: xc = xt @ afc   (clobbers ybuf region - y2 dead)
    gemm_k<64, 64, 8, 4, 4, false, false, false><<<dim3(VCC / 64, MM / 64), 256, 0, stream>>>(
        xt, VV, afc, VCC, nullptr, 0, nullptr, xc, VCC, VV, 1.0f);
    // K5: sxg = xc @ acs
    gemm_k<64, 64, 8, 4, 4, false, false, false><<<dim3(1, MM / 64), 256, 0, stream>>>(
        xc, VCC, acs, SS, nullptr, 0, nullptr, sxg, SS, VCC, 1.0f);
    // K6: coarse chanmix: yc0, yc12 (interleaved [M, 2*VC])
    chanmix_k<true, true><<<dim3(12, 16), 256, 0, stream>>>(xc, W, LL * VCC, VCC, yc0, yc12, 2 * VCC, 0, 1);
    // K7: super chanmix: ys0, ys12
    chanmix_k<true, true><<<dim3(3, 16), 256, 0, stream>>>(sxg, W, LL * SS, SS, ys0, ys12, 2 * SS, 0, 1);
    // K8: as_mat
    asmat_k<<<dim3(64), 64, 0, stream>>>(sxg, am);
    // K9: super supports
    supbuild_k<<<dim3(1), 64, 0, stream>>>(am, sups);
    // K10: hc = yc0 + yc12 @ [Ac1;Ac2] + bias
    gemm_k<64, 64, 8, 4, 4, false, true, true><<<dim3(VCC / 64, MM / 64), 256, 0, stream>>>(
        yc12, 2 * VCC, supc, VCC, yc0, VCC, b, hc, VCC, 2 * VCC, 1.0f);
    // K11: hs = ys0 + ys12 @ [As1;As2] + bias
    gemm_k<64, 64, 8, 4, 4, false, true, true><<<dim3(1, MM / 64), 256, 0, stream>>>(
        ys12, 2 * SS, sups, SS, ys0, SS, b, hs, SS, 2 * SS, 1.0f);
    // K12: transposes of acs, afc
    transpose2d<<<dim3(VCC / 32, VV / 32), 256, 0, stream>>>(afc, afcT, VV, VCC);
    transpose2d<<<dim3(SS / 32, VCC / 32), 256, 0, stream>>>(acs, acsT, VCC, SS);
    // K13: hc += 0.8 * relu(hs @ acs^T)
    gemm_k<64, 64, 8, 4, 4, true, true, false><<<dim3(VCC / 64, MM / 64), 256, 0, stream>>>(
        hs, SS, acsT, VCC, hc, VCC, nullptr, hc, VCC, SS, 0.8f);
    // K14: hf += 0.2 * relu(hc @ afc^T)
    gemm_k<128, 128, 8, 8, 8, true, true, false><<<dim3(VV / 128, MM / 128), 256, 0, stream>>>(
        hc, VCC, afcT, VV, hf, VV, nullptr, hf, VV, VCC, 0.2f);
    // K15: hc += 0.2 * relu(hf @ afc)
    gemm_k<64, 64, 8, 4, 4, true, true, false><<<dim3(VCC / 64, MM / 64), 256, 0, stream>>>(
        hf, VV, afc, VCC, hc, VCC, nullptr, hc, VCC, VV, 0.2f);
    // K16: hs += 0.2 * relu(hc @ acs)
    gemm_k<64, 64, 8, 4, 4, true, true, false><<<dim3(1, MM / 64), 256, 0, stream>>>(
        hc, VCC, acs, SS, hs, SS, nullptr, hs, SS, VCC, 0.2f);
    // K17: node-last -> reference layout [*, node, L]
    transpose_lv<<<dim3(VV / 128, NB * CO), 256, 0, stream>>>(hf, hf_out, VV, 128);
    transpose_lv<<<dim3(VCC / 128, NB * CO), 256, 0, stream>>>(hc, hc_out, VCC, 128);
    transpose_lv<<<dim3(1, NB * CO), 256, 0, stream>>>(hs, hs_out, SS, 64);
}

// Round 2
// 2169.866 us; speedup vs baseline: 1.3005x; 1.3005x over previous
//
#include <hip/hip_runtime.h>

// ---------------- problem dims ----------------
constexpr int NB = 16;    // batch
constexpr int CC = 32;    // in channels
constexpr int VV = 2048;  // fine nodes
constexpr int VCC = 256;  // coarse nodes
constexpr int SS = 64;    // super nodes
constexpr int LL = 12;    // time
constexpr int CO = 32;    // out channels
constexpr long MM = (long)NB * CO * LL;  // 6144 rows in node-last layout

// =====================================================================
// K1: x [nc, V, 12] -> xt [nc, 12, V]
__global__ __launch_bounds__(256)
void transpose_vl(const float* __restrict__ in, float* __restrict__ out) {
    __shared__ float t[128 * 12];
    const long nc = blockIdx.y;
    const int v0 = blockIdx.x * 128;
    const float* src = in + (nc * VV + v0) * 12;
    for (int f = threadIdx.x; f < 128 * 12; f += 256) t[f] = src[f];
    __syncthreads();
    float* dst = out + nc * 12L * VV;
    for (int g = threadIdx.x; g < 128 * 12; g += 256) {
        int l = g >> 7, vv = g & 127;
        dst[(long)l * VV + v0 + vv] = t[vv * 12 + l];
    }
}

// K17: in [nc, 12, Kn] -> out [nc, Kn, 12]   (TW = tile width over Kn)
__global__ __launch_bounds__(256)
void transpose_lv(const float* __restrict__ in, float* __restrict__ out, int Kn, int TW) {
    __shared__ float t[128 * 12];
    const long nc = blockIdx.y;
    const int v0 = blockIdx.x * TW;
    const float* src = in + nc * 12L * Kn;
    for (int g = threadIdx.x; g < TW * 12; g += 256) {
        int l = g / TW, vv = g - l * TW;
        t[vv * 12 + l] = src[(long)l * Kn + v0 + vv];
    }
    __syncthreads();
    float* dst = out + (nc * Kn + v0) * 12L;
    for (int f = threadIdx.x; f < TW * 12; f += 256) dst[f] = t[f];
}

// small dense transpose: in [rows, cols] -> out [cols, rows]
__global__ __launch_bounds__(256)
void transpose2d(const float* __restrict__ in, float* __restrict__ out, int rows, int cols) {
    __shared__ float t[32][33];
    const int r0 = blockIdx.y * 32, c0 = blockIdx.x * 32;
    const int ty = threadIdx.x / 32, tx = threadIdx.x % 32;
    for (int i = ty; i < 32; i += 8) t[i][tx] = in[(long)(r0 + i) * cols + c0 + tx];
    __syncthreads();
    for (int i = ty; i < 32; i += 8) out[(long)(c0 + i) * rows + r0 + tx] = t[tx][i];
}

// =====================================================================
// channel mix: in [16, 32, R] node-last, W [32,96].
template <bool DO0, bool DO2>
__global__ __launch_bounds__(256)
void chanmix_k(const float* __restrict__ in, const float* __restrict__ Wt,
               int R, int Kn, float* __restrict__ o0,
               float* __restrict__ o1, int ld1, int co1, int j1) {
    __shared__ float Ws[CO * 96];
    for (int idx = threadIdx.x; idx < CO * 96; idx += 256) Ws[idx] = Wt[idx];
    __syncthreads();
    const int nb = blockIdx.y;
    const int r = blockIdx.x * 256 + threadIdx.x;
    if (r >= R) return;
    const int l = r / Kn, k = r - l * Kn;
    float xv[CC];
#pragma unroll
    for (int c = 0; c < CC; ++c) xv[c] = in[((long)(nb * CC + c)) * R + r];
    for (int o = 0; o < CO; ++o) {
        float a0 = 0.f, a1 = 0.f, a2 = 0.f;
#pragma unroll
        for (int c = 0; c < CC; ++c) {
            const float x = xv[c];
            if (DO0) a0 = fmaf(Ws[o * 96 + c], x, a0);
            a1 = fmaf(Ws[o * 96 + j1 * 32 + c], x, a1);
            if (DO2) a2 = fmaf(Ws[o * 96 + 64 + c], x, a2);
        }
        const long mrow = (long)(nb * CO + o) * LL + l;
        if (DO0) o0[mrow * Kn + k] = a0;
        o1[mrow * ld1 + co1 + k] = a1;
        if (DO2) o1[mrow * ld1 + co1 + Kn + k] = a2;
    }
}

// =====================================================================
// generic fp32 GEMM (see round 0 notes)
template <int BM, int BN, int BK, int TM, int TN, bool RELU, bool ADDC0, bool BIAS>
__global__ __launch_bounds__(256)
void gemm_k(const float* __restrict__ X, int ldx,
            const float* __restrict__ Bm, int ldb,
            const float* __restrict__ C0, int ldc,
            const float* __restrict__ bias,
            float* __restrict__ Out, int ldo, int K, float alpha) {
    constexpr int TX = BN / TN;            // threads along n
    constexpr int LX = (BM * BK) / 256;    // floats/thread X tile
    constexpr int LB = (BN * BK) / 256;    // floats/thread B tile
    __shared__ float Xs[BK][BM + 4];
    __shared__ float Bs[BK][BN + 4];
    const int tid = threadIdx.x;
    const int tx = tid % TX, ty = tid / TX;
    const long m0 = (long)blockIdx.y * BM;
    const int n0 = blockIdx.x * BN;
    const int xr = tid / (BK / LX);
    const int xcc = (tid % (BK / LX)) * LX;
    const int br = tid / (BN / LB);
    const int bc = (tid % (BN / LB)) * LB;

    float acc[TM][TN];
#pragma unroll
    for (int i = 0; i < TM; ++i)
#pragma unroll
        for (int j = 0; j < TN; ++j) acc[i][j] = 0.f;

    const float* Xp = X + (m0 + xr) * (long)ldx + xcc;
    const float* Bp = Bm + (long)br * ldb + n0 + bc;

    for (int k0 = 0; k0 < K; k0 += BK) {
        if constexpr (LX == 4) {
            const float4 v = *(const float4*)Xp;
            Xs[xcc + 0][xr] = v.x; Xs[xcc + 1][xr] = v.y;
            Xs[xcc + 2][xr] = v.z; Xs[xcc + 3][xr] = v.w;
        } else {
            const float2 v = *(const float2*)Xp;
            Xs[xcc + 0][xr] = v.x; Xs[xcc + 1][xr] = v.y;
        }
        if constexpr (LB == 4) {
            *(float4*)&Bs[br][bc] = *(const float4*)Bp;
        } else {
            *(float2*)&Bs[br][bc] = *(const float2*)Bp;
        }
        __syncthreads();
#pragma unroll
        for (int kk = 0; kk < BK; ++kk) {
            float a[TM], b[TN];
#pragma unroll
            for (int i = 0; i < TM; ++i) a[i] = Xs[kk][ty * TM + i];
#pragma unroll
            for (int j = 0; j < TN; ++j) b[j] = Bs[kk][tx * TN + j];
#pragma unroll
            for (int i = 0; i < TM; ++i)
#pragma unroll
                for (int j = 0; j < TN; ++j) acc[i][j] = fmaf(a[i], b[j], acc[i][j]);
        }
        __syncthreads();
        Xp += BK;
        Bp += (long)BK * ldb;
    }

#pragma unroll
    for (int i = 0; i < TM; ++i) {
        const long m = m0 + (long)ty * TM + i;
        float bv = 0.f;
        if (BIAS) bv = bias[(int)((m / LL) & (CO - 1))];
        const long obase = m * (long)ldo + n0 + tx * TN;
        long cbase = 0;
        if constexpr (ADDC0) cbase = m * (long)ldc + n0 + tx * TN;
#pragma unroll
        for (int j = 0; j < TN; ++j) {
            float p = acc[i][j];
            if (RELU) p = fmaxf(p, 0.f);
            p *= alpha;
            float c = 0.f;
            if constexpr (ADDC0) c = C0[cbase + j];
            Out[obase + j] = c + p + bv;
        }
    }
}

// =====================================================================
// zero a small float buffer
__global__ __launch_bounds__(256)
void zero_k(float* __restrict__ p, int n) {
    for (int i = blockIdx.x * 256 + threadIdx.x; i < n; i += gridDim.x * 256) p[i] = 0.f;
}

// split-K Gram: am_raw[s,t] += sum_{i in block-slice} sxg[rowA(i)][s]*sxg[rowB(i)][t]
// rowA: i flattened (c,n,l); rowB: i flattened (l,n,c)  [faithful mismatched orders]
// grid: 48 blocks x 256 thr; each block covers 128 i-values, LDS-staged, 4x4 microtile.
__global__ __launch_bounds__(256)
void asmat_split(const float* __restrict__ sxg, float* __restrict__ am_raw) {
    __shared__ float Us[128][65];
    __shared__ float Wsh[128][65];
    __shared__ int rA[128], rB[128];
    const int i0 = blockIdx.x * 128;
    const int tid = threadIdx.x;
    if (tid < 128) {
        const int i = i0 + tid;
        const int c = i / 192;
        const int rem = i - c * 192;
        const int n = rem / 12;
        const int l = rem - n * 12;
        rA[tid] = (n * 32 + c) * 12 + l;
        const int l2 = i >> 9;
        const int rem2 = i & 511;
        rB[tid] = ((rem2 >> 5) * 32 + (rem2 & 31)) * 12 + l2;
    }
    __syncthreads();
    for (int idx = tid; idx < 128 * 64; idx += 256) {
        const int r = idx >> 6, s = idx & 63;
        Us[r][s] = sxg[rA[r] * 64 + s];
        Wsh[r][s] = sxg[rB[r] * 64 + s];
    }
    __syncthreads();
    const int ts = (tid & 15) * 4;
    const int tt = (tid >> 4) * 4;
    float acc[4][4];
#pragma unroll
    for (int i2 = 0; i2 < 4; ++i2)
#pragma unroll
        for (int j = 0; j < 4; ++j) acc[i2][j] = 0.f;
    for (int k = 0; k < 128; ++k) {
        float a[4], bv[4];
#pragma unroll
        for (int i2 = 0; i2 < 4; ++i2) a[i2] = Us[k][ts + i2];
#pragma unroll
        for (int j = 0; j < 4; ++j) bv[j] = Wsh[k][tt + j];
#pragma unroll
        for (int i2 = 0; i2 < 4; ++i2)
#pragma unroll
            for (int j = 0; j < 4; ++j) acc[i2][j] = fmaf(a[i2], bv[j], acc[i2][j]);
    }
#pragma unroll
    for (int i2 = 0; i2 < 4; ++i2)
#pragma unroll
        for (int j = 0; j < 4; ++j)
            atomicAdd(&am_raw[(ts + i2) * 64 + tt + j], acc[i2][j]);
}

// sup[0] = softmax(rownorm(relu(raw-0.5))), sup[1] = same on transpose
__global__ __launch_bounds__(64)
void supbuild_k(const float* __restrict__ am_raw, float* __restrict__ sup) {
    __shared__ float a[64][65];
    for (int idx = threadIdx.x; idx < 4096; idx += 64) {
        const float v = am_raw[idx] - 0.5f;
        a[idx >> 6][idx & 63] = v > 0.f ? v : 0.f;
    }
    __syncthreads();
    const int r = threadIdx.x;
    {
        float rs = 0.f;
        for (int j = 0; j < 64; ++j) rs += a[r][j];
        const float dinv = rs > 0.f ? 1.f / rs : 0.f;
        float mx = -1e30f;
        for (int j = 0; j < 64; ++j) mx = fmaxf(mx, a[r][j] * dinv);
        float se = 0.f;
        for (int j = 0; j < 64; ++j) se += expf(a[r][j] * dinv - mx);
        const float inv = 1.f / se;
        for (int j = 0; j < 64; ++j) sup[r * 64 + j] = expf(a[r][j] * dinv - mx) * inv;
    }
    {
        float rs = 0.f;
        for (int j = 0; j < 64; ++j) rs += a[j][r];
        const float dinv = rs > 0.f ? 1.f / rs : 0.f;
        float mx = -1e30f;
        for (int j = 0; j < 64; ++j) mx = fmaxf(mx, a[j][r] * dinv);
        float se = 0.f;
        for (int j = 0; j < 64; ++j) se += expf(a[j][r] * dinv - mx);
        const float inv = 1.f / se;
        for (int j = 0; j < 64; ++j) sup[4096 + r * 64 + j] = expf(a[j][r] * dinv - mx) * inv;
    }
}

// =====================================================================
extern "C" void kernel_launch(void* const* d_in, const int* in_sizes, int n_in,
                              void* d_out, int out_size, void* d_ws, size_t ws_size,
                              hipStream_t stream) {
    (void)in_sizes; (void)n_in; (void)out_size; (void)ws_size;
    const float* x    = (const float*)d_in[0];
    const float* sup  = (const float*)d_in[1];  // [2, V, V]
    const float* supc = (const float*)d_in[2];  // [2, VC, VC]
    const float* acs  = (const float*)d_in[3];  // [VC, S]
    const float* afc  = (const float*)d_in[4];  // [V, VC]
    const float* W    = (const float*)d_in[5];  // [32, 96]
    const float* b    = (const float*)d_in[6];  // [32]
    float* ws = (float*)d_ws;

    float* xt   = ws;                   // 12,582,912  [nc,12,V]
    float* hf   = ws + 12582912L;       // 12,582,912  y0 then hf (in-place)
    float* ybuf = ws + 25165824L;       // 12,582,912  y1 then y2
    float* xc   = ws + 25165824L;       // aliases ybuf (y dead after K3b)
    float* sxg  = ws + 26738688L;
    float* yc0  = ws + 27131904L;
    float* yc12 = ws + 28704768L;
    float* ys0  = ws + 31850496L;
    float* ys12 = ws + 32243712L;
    float* hc   = ws + 33030144L;
    float* hs   = ws + 34603008L;
    float* am   = ws + 34996224L;       // raw gram accumulator (4096)
    float* sups = ws + 35000320L;
    float* acsT = ws + 35008512L;
    float* afcT = ws + 35024896L;

    float* hf_out = (float*)d_out;
    float* hc_out = hf_out + 12582912L;
    float* hs_out = hf_out + 14155776L;

    // K1: xt = transpose(x)
    transpose_vl<<<dim3(VV / 128, NB * CC), 256, 0, stream>>>(x, xt);
    // K2a: y0 -> hf, y1 -> ybuf
    chanmix_k<true, false><<<dim3(96, 16), 256, 0, stream>>>(xt, W, LL * VV, VV, hf, ybuf, VV, 0, 1);
    // K3a: hf = y0 + y1@A1 + bias
    gemm_k<128, 128, 8, 8, 8, false, true, true><<<dim3(VV / 128, MM / 128), 256, 0, stream>>>(
        ybuf, VV, sup, VV, hf, VV, b, hf, VV, VV, 1.0f);
    // K2b: y2 -> ybuf
    chanmix_k<false, false><<<dim3(96, 16), 256, 0, stream>>>(xt, W, LL * VV, VV, nullptr, ybuf, VV, 0, 2);
    // K3b: hf += y2@A2
    gemm_k<128, 128, 8, 8, 8, false, true, false><<<dim3(VV / 128, MM / 128), 256, 0, stream>>>(
        ybuf, VV, sup + (long)VV * VV, VV, hf, VV, nullptr, hf, VV, VV, 1.0f);
    // K4: xc = xt @ afc   (clobbers ybuf region - y2 dead)
    gemm_k<64, 64, 8, 4, 4, false, false, false><<<dim3(VCC / 64, MM / 64), 256, 0, stream>>>(
        xt, VV, afc, VCC, nullptr, 0, nullptr, xc, VCC, VV, 1.0f);
    // K5: sxg = xc @ acs
    gemm_k<64, 64, 8, 4, 4, false, false, false><<<dim3(1, MM / 64), 256, 0, stream>>>(
        xc, VCC, acs, SS, nullptr, 0, nullptr, sxg, SS, VCC, 1.0f);
    // K6: coarse chanmix
    chanmix_k<true, true><<<dim3(12, 16), 256, 0, stream>>>(xc, W, LL * VCC, VCC, yc0, yc12, 2 * VCC, 0, 1);
    // K7: super chanmix
    chanmix_k<true, true><<<dim3(3, 16), 256, 0, stream>>>(sxg, W, LL * SS, SS, ys0, ys12, 2 * SS, 0, 1);
    // K8: as_mat (zero accumulator, split-K gram, 48 blocks)
    zero_k<<<dim3(4), 256, 0, stream>>>(am, 4096);
    asmat_split<<<dim3(48), 256, 0, stream>>>(sxg, am);
    // K9: super supports (relu(x-0.5) fused on load)
    supbuild_k<<<dim3(1), 64, 0, stream>>>(am, sups);
    // K10: hc = yc0 + yc12 @ [Ac1;Ac2] + bias
    gemm_k<64, 64, 8, 4, 4, false, true, true><<<dim3(VCC / 64, MM / 64), 256, 0, stream>>>(
        yc12, 2 * VCC, supc, VCC, yc0, VCC, b, hc, VCC, 2 * VCC, 1.0f);
    // K11: hs = ys0 + ys12 @ [As1;As2] + bias
    gemm_k<64, 64, 8, 4, 4, false, true, true><<<dim3(1, MM / 64), 256, 0, stream>>>(
        ys12, 2 * SS, sups, SS, ys0, SS, b, hs, SS, 2 * SS, 1.0f);
    // K12: transposes of acs, afc
    transpose2d<<<dim3(VCC / 32, VV / 32), 256, 0, stream>>>(afc, afcT, VV, VCC);
    transpose2d<<<dim3(SS / 32, VCC / 32), 256, 0, stream>>>(acs, acsT, VCC, SS);
    // K13: hc += 0.8 * relu(hs @ acs^T)
    gemm_k<64, 64, 8, 4, 4, true, true, false><<<dim3(VCC / 64, MM / 64), 256, 0, stream>>>(
        hs, SS, acsT, VCC, hc, VCC, nullptr, hc, VCC, SS, 0.8f);
    // K14: hf += 0.2 * relu(hc @ afc^T)
    gemm_k<128, 128, 8, 8, 8, true, true, false><<<dim3(VV / 128, MM / 128), 256, 0, stream>>>(
        hc, VCC, afcT, VV, hf, VV, nullptr, hf, VV, VCC, 0.2f);
    // K15: hc += 0.2 * relu(hf @ afc)
    gemm_k<64, 64, 8, 4, 4, true, true, false><<<dim3(VCC / 64, MM / 64), 256, 0, stream>>>(
        hf, VV, afc, VCC, hc, VCC, nullptr, hc, VCC, VV, 0.2f);
    // K16: hs += 0.2 * relu(hc @ acs)
    gemm_k<64, 64, 8, 4, 4, true, true, false><<<dim3(1, MM / 64), 256, 0, stream>>>(
        hc, VCC, acs, SS, hs, SS, nullptr, hs, SS, VCC, 0.2f);
    // K17: node-last -> reference layout [*, node, L]
    transpose_lv<<<dim3(VV / 128, NB * CO), 256, 0, stream>>>(hf, hf_out, VV, 128);
    transpose_lv<<<dim3(VCC / 128, NB * CO), 256, 0, stream>>>(hc, hc_out, VCC, 128);
    transpose_lv<<<dim3(1, NB * CO), 256, 0, stream>>>(hs, hs_out, SS, 64);
}

// Round 3
// 867.511 us; speedup vs baseline: 3.2529x; 2.5013x over previous
//
#include <hip/hip_runtime.h>

// ---------------- problem dims ----------------
constexpr int NB = 16;    // batch
constexpr int CC = 32;    // in channels
constexpr int VV = 2048;  // fine nodes
constexpr int VCC = 256;  // coarse nodes
constexpr int SS = 64;    // super nodes
constexpr int LL = 12;    // time
constexpr int CO = 32;    // out channels
constexpr long MM = (long)NB * CO * LL;  // 6144 rows in node-last layout

typedef __attribute__((ext_vector_type(8))) __bf16 bf16x8;
typedef __attribute__((ext_vector_type(4))) float f32x4;

__device__ __forceinline__ unsigned short f2bf(float f) {
    unsigned u = __float_as_uint(f);
    unsigned r = u + 0x7FFFu + ((u >> 16) & 1u);  // RNE
    return (unsigned short)(r >> 16);
}

__device__ __forceinline__ void gl_lds16(const void* g, void* l) {
    __builtin_amdgcn_global_load_lds(
        (const __attribute__((address_space(1))) void*)g,
        (__attribute__((address_space(3))) void*)l, 16, 0, 0);
}

// =====================================================================
// K1: x [nc, V, 12] -> xt [nc, 12, V]
__global__ __launch_bounds__(256)
void transpose_vl(const float* __restrict__ in, float* __restrict__ out) {
    __shared__ float t[128 * 12];
    const long nc = blockIdx.y;
    const int v0 = blockIdx.x * 128;
    const float* src = in + (nc * VV + v0) * 12;
    for (int f = threadIdx.x; f < 128 * 12; f += 256) t[f] = src[f];
    __syncthreads();
    float* dst = out + nc * 12L * VV;
    for (int g = threadIdx.x; g < 128 * 12; g += 256) {
        int l = g >> 7, vv = g & 127;
        dst[(long)l * VV + v0 + vv] = t[vv * 12 + l];
    }
}

// out-transpose: in [nc, 12, Kn] -> out [nc, Kn, 12]
__global__ __launch_bounds__(256)
void transpose_lv(const float* __restrict__ in, float* __restrict__ out, int Kn, int TW) {
    __shared__ float t[128 * 12];
    const long nc = blockIdx.y;
    const int v0 = blockIdx.x * TW;
    const float* src = in + nc * 12L * Kn;
    for (int g = threadIdx.x; g < TW * 12; g += 256) {
        int l = g / TW, vv = g - l * TW;
        t[vv * 12 + l] = src[(long)l * Kn + v0 + vv];
    }
    __syncthreads();
    float* dst = out + (nc * Kn + v0) * 12L;
    for (int f = threadIdx.x; f < TW * 12; f += 256) dst[f] = t[f];
}

// small dense fp32 transpose: in [rows, cols] -> out [cols, rows]
__global__ __launch_bounds__(256)
void transpose2d(const float* __restrict__ in, float* __restrict__ out, int rows, int cols) {
    __shared__ float t[32][33];
    const int r0 = blockIdx.y * 32, c0 = blockIdx.x * 32;
    const int ty = threadIdx.x / 32, tx = threadIdx.x % 32;
    for (int i = ty; i < 32; i += 8) t[i][tx] = in[(long)(r0 + i) * cols + c0 + tx];
    __syncthreads();
    for (int i = ty; i < 32; i += 8) out[(long)(c0 + i) * rows + r0 + tx] = t[tx][i];
}

// fp32 -> bf16 elementwise (n % 4 == 0)
__global__ __launch_bounds__(256)
void cvt_bf16_k(const float* __restrict__ in, unsigned short* __restrict__ out, long n) {
    long i = ((long)blockIdx.x * 256 + threadIdx.x) * 4;
    if (i >= n) return;
    const float4 v = *(const float4*)(in + i);
    ushort4 o;
    o.x = f2bf(v.x); o.y = f2bf(v.y); o.z = f2bf(v.z); o.w = f2bf(v.w);
    *(ushort4*)(out + i) = o;
}

// fp32 [R,C] -> bf16 transpose [C,R]
__global__ __launch_bounds__(256)
void cvt_T_bf16_k(const float* __restrict__ in, unsigned short* __restrict__ out,
                  int R, int Ccols) {
    __shared__ float t[32][33];
    const int r0 = blockIdx.y * 32, c0 = blockIdx.x * 32;
    const int ty = threadIdx.x / 32, tx = threadIdx.x % 32;
    for (int i = ty; i < 32; i += 8) t[i][tx] = in[(long)(r0 + i) * Ccols + c0 + tx];
    __syncthreads();
    for (int i = ty; i < 32; i += 8) out[(long)(c0 + i) * R + r0 + tx] = f2bf(t[tx][i]);
}

// =====================================================================
// fine channel mix, single pass: xt [16,32,24576] -> y0 fp32 [M,2048],
// y12 bf16 [M,4096] (cols [y1 | y2])
__global__ __launch_bounds__(256)
void chanmix_fine(const float* __restrict__ in, const float* __restrict__ Wt,
                  float* __restrict__ y0, unsigned short* __restrict__ y12) {
    __shared__ float Ws[CO * 96];
    for (int idx = threadIdx.x; idx < CO * 96; idx += 256) Ws[idx] = Wt[idx];
    __syncthreads();
    const int nb = blockIdx.y;
    const int r = blockIdx.x * 256 + threadIdx.x;
    const int R = LL * VV;
    const int l = r / VV, k = r - l * VV;
    float xv[CC];
#pragma unroll
    for (int c = 0; c < CC; ++c) xv[c] = in[((long)(nb * CC + c)) * R + r];
    for (int o = 0; o < CO; ++o) {
        float a0 = 0.f, a1 = 0.f, a2 = 0.f;
#pragma unroll
        for (int c = 0; c < CC; ++c) {
            const float x = xv[c];
            a0 = fmaf(Ws[o * 96 + c], x, a0);
            a1 = fmaf(Ws[o * 96 + 32 + c], x, a1);
            a2 = fmaf(Ws[o * 96 + 64 + c], x, a2);
        }
        const long mrow = (long)(nb * CO + o) * LL + l;
        y0[mrow * VV + k] = a0;
        y12[mrow * 4096 + k] = f2bf(a1);
        y12[mrow * 4096 + 2048 + k] = f2bf(a2);
    }
}

// coarse/super channel mix (fp32 outputs, as round 2)
__global__ __launch_bounds__(256)
void chanmix_k(const float* __restrict__ in, const float* __restrict__ Wt,
               int R, int Kn, float* __restrict__ o0,
               float* __restrict__ o1, int ld1) {
    __shared__ float Ws[CO * 96];
    for (int idx = threadIdx.x; idx < CO * 96; idx += 256) Ws[idx] = Wt[idx];
    __syncthreads();
    const int nb = blockIdx.y;
    const int r = blockIdx.x * 256 + threadIdx.x;
    if (r >= R) return;
    const int l = r / Kn, k = r - l * Kn;
    float xv[CC];
#pragma unroll
    for (int c = 0; c < CC; ++c) xv[c] = in[((long)(nb * CC + c)) * R + r];
    for (int o = 0; o < CO; ++o) {
        float a0 = 0.f, a1 = 0.f, a2 = 0.f;
#pragma unroll
        for (int c = 0; c < CC; ++c) {
            const float x = xv[c];
            a0 = fmaf(Ws[o * 96 + c], x, a0);
            a1 = fmaf(Ws[o * 96 + 32 + c], x, a1);
            a2 = fmaf(Ws[o * 96 + 64 + c], x, a2);
        }
        const long mrow = (long)(nb * CO + o) * LL + l;
        o0[mrow * Kn + k] = a0;
        o1[mrow * ld1 + k] = a1;
        o1[mrow * ld1 + Kn + k] = a2;
    }
}

// =====================================================================
// bf16 MFMA GEMM: Out[m,n] = C0[m,n] + (BIAS? bias[(m/12)&31]:0)
//                           + alpha * (RELU? relu(A@B) : A@B)
// A [M,K] bf16 row-major (lda), Bt [N,K] bf16 row-major (ldb)  (i.e. B^T).
// Tile 128x128, BK=64, 4 waves (2x2 of 64x64), 16x16x32 MFMA, XOR-swizzled LDS,
// global_load_lds width-16 staging. M%128==0, N%128==0, K%64==0.
template <bool RELU, bool BIAS>
__global__ __launch_bounds__(256)
void gemm_mfma(const unsigned short* __restrict__ A, int lda,
               const unsigned short* __restrict__ Bt, int ldb,
               const float* __restrict__ C0, int ldc,
               const float* __restrict__ bias,
               float* __restrict__ Out, int ldo, int K, float alpha) {
    __shared__ __align__(16) unsigned short As[128 * 64];
    __shared__ __align__(16) unsigned short Bs[128 * 64];
    const int tid = threadIdx.x;
    const int lane = tid & 63;
    const int w = tid >> 6;
    const long m0 = (long)blockIdx.y * 128;
    const int n0 = blockIdx.x * 128;

    // staging: chunk t = q*256 + tid; LDS row = t>>3, slot pos = t&7 holds
    // logical k-chunk lc = pos ^ (row&7)  (16B granular XOR swizzle)
    long offA[4], offB[4];
#pragma unroll
    for (int q = 0; q < 4; ++q) {
        const int t = q * 256 + tid;
        const int row = t >> 3, pos = t & 7;
        const int lc = pos ^ (row & 7);
        offA[q] = (m0 + row) * (long)lda + lc * 8;
        offB[q] = (long)(n0 + row) * ldb + lc * 8;
    }
    const int wm = (w & 1) * 64, wn = (w >> 1) * 64;
    const int mrow = lane & 15;   // row/col within a 16-tile
    const int quad = lane >> 4;

    f32x4 acc[4][4];
#pragma unroll
    for (int i = 0; i < 4; ++i)
#pragma unroll
        for (int j = 0; j < 4; ++j) acc[i][j] = (f32x4){0.f, 0.f, 0.f, 0.f};

    for (int k0 = 0; k0 < K; k0 += 64) {
#pragma unroll
        for (int q = 0; q < 4; ++q)
            gl_lds16(A + offA[q] + k0, &As[(q * 256 + w * 64) * 8]);
#pragma unroll
        for (int q = 0; q < 4; ++q)
            gl_lds16(Bt + offB[q] + k0, &Bs[(q * 256 + w * 64) * 8]);
        __syncthreads();
#pragma unroll
        for (int ks = 0; ks < 2; ++ks) {
            bf16x8 af[4], bfr[4];
            const int pos = (ks * 4 + quad) ^ (mrow & 7);
#pragma unroll
            for (int tm = 0; tm < 4; ++tm) {
                const int r = wm + tm * 16 + mrow;
                af[tm] = *(const bf16x8*)&As[r * 64 + pos * 8];
            }
#pragma unroll
            for (int tn = 0; tn < 4; ++tn) {
                const int r = wn + tn * 16 + mrow;
                bfr[tn] = *(const bf16x8*)&Bs[r * 64 + pos * 8];
            }
#pragma unroll
            for (int tm = 0; tm < 4; ++tm)
#pragma unroll
                for (int tn = 0; tn < 4; ++tn)
                    acc[tm][tn] = __builtin_amdgcn_mfma_f32_16x16x32_bf16(
                        af[tm], bfr[tn], acc[tm][tn], 0, 0, 0);
        }
        __syncthreads();
    }

    // C/D layout: col = lane&15, row = quad*4 + reg  [m89/m91 verified]
#pragma unroll
    for (int tm = 0; tm < 4; ++tm) {
#pragma unroll
        for (int tn = 0; tn < 4; ++tn) {
            const int n = n0 + wn + tn * 16 + mrow;
#pragma unroll
            for (int reg = 0; reg < 4; ++reg) {
                const long m = m0 + wm + tm * 16 + quad * 4 + reg;
                float p = acc[tm][tn][reg];
                if (RELU) p = fmaxf(p, 0.f);
                p *= alpha;
                float c = C0[m * (long)ldc + n];
                if (BIAS) c += bias[(int)((m / LL) & (CO - 1))];
                Out[m * (long)ldo + n] = c + p;
            }
        }
    }
}

// =====================================================================
// generic fp32 GEMM (kept for narrow / accuracy-critical ops)
template <int BM, int BN, int BK, int TM, int TN, bool RELU, bool ADDC0, bool BIAS>
__global__ __launch_bounds__(256)
void gemm_k(const float* __restrict__ X, int ldx,
            const float* __restrict__ Bm, int ldb,
            const float* __restrict__ C0, int ldc,
            const float* __restrict__ bias,
            float* __restrict__ Out, int ldo, int K, float alpha) {
    constexpr int TX = BN / TN;
    constexpr int LX = (BM * BK) / 256;
    constexpr int LB = (BN * BK) / 256;
    __shared__ float Xs[BK][BM + 4];
    __shared__ float Bs[BK][BN + 4];
    const int tid = threadIdx.x;
    const int tx = tid % TX, ty = tid / TX;
    const long m0 = (long)blockIdx.y * BM;
    const int n0 = blockIdx.x * BN;
    const int xr = tid / (BK / LX);
    const int xcc = (tid % (BK / LX)) * LX;
    const int br = tid / (BN / LB);
    const int bc = (tid % (BN / LB)) * LB;

    float acc[TM][TN];
#pragma unroll
    for (int i = 0; i < TM; ++i)
#pragma unroll
        for (int j = 0; j < TN; ++j) acc[i][j] = 0.f;

    const float* Xp = X + (m0 + xr) * (long)ldx + xcc;
    const float* Bp = Bm + (long)br * ldb + n0 + bc;

    for (int k0 = 0; k0 < K; k0 += BK) {
        if constexpr (LX == 4) {
            const float4 v = *(const float4*)Xp;
            Xs[xcc + 0][xr] = v.x; Xs[xcc + 1][xr] = v.y;
            Xs[xcc + 2][xr] = v.z; Xs[xcc + 3][xr] = v.w;
        } else {
            const float2 v = *(const float2*)Xp;
            Xs[xcc + 0][xr] = v.x; Xs[xcc + 1][xr] = v.y;
        }
        if constexpr (LB == 4) {
            *(float4*)&Bs[br][bc] = *(const float4*)Bp;
        } else {
            *(float2*)&Bs[br][bc] = *(const float2*)Bp;
        }
        __syncthreads();
#pragma unroll
        for (int kk = 0; kk < BK; ++kk) {
            float a[TM], b[TN];
#pragma unroll
            for (int i = 0; i < TM; ++i) a[i] = Xs[kk][ty * TM + i];
#pragma unroll
            for (int j = 0; j < TN; ++j) b[j] = Bs[kk][tx * TN + j];
#pragma unroll
            for (int i = 0; i < TM; ++i)
#pragma unroll
                for (int j = 0; j < TN; ++j) acc[i][j] = fmaf(a[i], b[j], acc[i][j]);
        }
        __syncthreads();
        Xp += BK;
        Bp += (long)BK * ldb;
    }

#pragma unroll
    for (int i = 0; i < TM; ++i) {
        const long m = m0 + (long)ty * TM + i;
        float bv = 0.f;
        if (BIAS) bv = bias[(int)((m / LL) & (CO - 1))];
        const long obase = m * (long)ldo + n0 + tx * TN;
        long cbase = 0;
        if constexpr (ADDC0) cbase = m * (long)ldc + n0 + tx * TN;
#pragma unroll
        for (int j = 0; j < TN; ++j) {
            float p = acc[i][j];
            if (RELU) p = fmaxf(p, 0.f);
            p *= alpha;
            float c = 0.f;
            if constexpr (ADDC0) c = C0[cbase + j];
            Out[obase + j] = c + p + bv;
        }
    }
}

// =====================================================================
__global__ __launch_bounds__(256)
void zero_k(float* __restrict__ p, int n) {
    for (int i = blockIdx.x * 256 + threadIdx.x; i < n; i += gridDim.x * 256) p[i] = 0.f;
}

// split-K Gram with mismatched flatten orders (faithful)
__global__ __launch_bounds__(256)
void asmat_split(const float* __restrict__ sxg, float* __restrict__ am_raw) {
    __shared__ float Us[128][65];
    __shared__ float Wsh[128][65];
    __shared__ int rA[128], rB[128];
    const int i0 = blockIdx.x * 128;
    const int tid = threadIdx.x;
    if (tid < 128) {
        const int i = i0 + tid;
        const int c = i / 192;
        const int rem = i - c * 192;
        const int n = rem / 12;
        const int l = rem - n * 12;
        rA[tid] = (n * 32 + c) * 12 + l;
        const int l2 = i >> 9;
        const int rem2 = i & 511;
        rB[tid] = ((rem2 >> 5) * 32 + (rem2 & 31)) * 12 + l2;
    }
    __syncthreads();
    for (int idx = tid; idx < 128 * 64; idx += 256) {
        const int r = idx >> 6, s = idx & 63;
        Us[r][s] = sxg[rA[r] * 64 + s];
        Wsh[r][s] = sxg[rB[r] * 64 + s];
    }
    __syncthreads();
    const int ts = (tid & 15) * 4;
    const int tt = (tid >> 4) * 4;
    float acc[4][4];
#pragma unroll
    for (int i2 = 0; i2 < 4; ++i2)
#pragma unroll
        for (int j = 0; j < 4; ++j) acc[i2][j] = 0.f;
    for (int k = 0; k < 128; ++k) {
        float a[4], bv[4];
#pragma unroll
        for (int i2 = 0; i2 < 4; ++i2) a[i2] = Us[k][ts + i2];
#pragma unroll
        for (int j = 0; j < 4; ++j) bv[j] = Wsh[k][tt + j];
#pragma unroll
        for (int i2 = 0; i2 < 4; ++i2)
#pragma unroll
            for (int j = 0; j < 4; ++j) acc[i2][j] = fmaf(a[i2], bv[j], acc[i2][j]);
    }
#pragma unroll
    for (int i2 = 0; i2 < 4; ++i2)
#pragma unroll
        for (int j = 0; j < 4; ++j)
            atomicAdd(&am_raw[(ts + i2) * 64 + tt + j], acc[i2][j]);
}

// sup[0] = softmax(rownorm(relu(raw-0.5))), sup[1] = same on transpose
__global__ __launch_bounds__(64)
void supbuild_k(const float* __restrict__ am_raw, float* __restrict__ sup) {
    __shared__ float a[64][65];
    for (int idx = threadIdx.x; idx < 4096; idx += 64) {
        const float v = am_raw[idx] - 0.5f;
        a[idx >> 6][idx & 63] = v > 0.f ? v : 0.f;
    }
    __syncthreads();
    const int r = threadIdx.x;
    {
        float rs = 0.f;
        for (int j = 0; j < 64; ++j) rs += a[r][j];
        const float dinv = rs > 0.f ? 1.f / rs : 0.f;
        float mx = -1e30f;
        for (int j = 0; j < 64; ++j) mx = fmaxf(mx, a[r][j] * dinv);
        float se = 0.f;
        for (int j = 0; j < 64; ++j) se += expf(a[r][j] * dinv - mx);
        const float inv = 1.f / se;
        for (int j = 0; j < 64; ++j) sup[r * 64 + j] = expf(a[r][j] * dinv - mx) * inv;
    }
    {
        float rs = 0.f;
        for (int j = 0; j < 64; ++j) rs += a[j][r];
        const float dinv = rs > 0.f ? 1.f / rs : 0.f;
        float mx = -1e30f;
        for (int j = 0; j < 64; ++j) mx = fmaxf(mx, a[j][r] * dinv);
        float se = 0.f;
        for (int j = 0; j < 64; ++j) se += expf(a[j][r] * dinv - mx);
        const float inv = 1.f / se;
        for (int j = 0; j < 64; ++j) sup[4096 + r * 64 + j] = expf(a[j][r] * dinv - mx) * inv;
    }
}

// =====================================================================
extern "C" void kernel_launch(void* const* d_in, const int* in_sizes, int n_in,
                              void* d_out, int out_size, void* d_ws, size_t ws_size,
                              hipStream_t stream) {
    (void)in_sizes; (void)n_in; (void)out_size; (void)ws_size;
    const float* x    = (const float*)d_in[0];
    const float* sup  = (const float*)d_in[1];  // [2, V, V]
    const float* supc = (const float*)d_in[2];  // [2, VC, VC]
    const float* acs  = (const float*)d_in[3];  // [VC, S]
    const float* afc  = (const float*)d_in[4];  // [V, VC]
    const float* W    = (const float*)d_in[5];  // [32, 96]
    const float* b    = (const float*)d_in[6];  // [32]
    float* ws = (float*)d_ws;

    // --- region A [0, 12,582,912): xt fp32; after chanmix_fine it is reused:
    float* xt = ws;
    unsigned short* Btu  = (unsigned short*)ws;               // bf16 [2048][4096] (B^T of [A1;A2])
    unsigned short* afcb = (unsigned short*)(ws + 4194304);   // bf16 [2048][256]  (= (afc^T)^T)
    float* yc0  = ws + 4456448;
    float* yc12 = ws + 6029312;
    float* ys0  = ws + 9175040;
    float* ys12 = ws + 9568256;
    float* hc   = ws + 10354688;
    float* hs   = ws + 11927552;
    float* am   = ws + 12320768;
    float* sups = ws + 12324864;
    float* acsT = ws + 12333056;                              // ends 12,349,440
    // --- fixed regions
    float* hf   = ws + 12582912;                              // y0 then hf
    float* xc   = ws + 25165824;
    float* sxg  = ws + 26738688;                              // ws total 27,131,904 fl (108.5 MB)

    // --- d_out doubles as scratch (dead before final output writes)
    float* out_f = (float*)d_out;
    unsigned short* y12u  = (unsigned short*)d_out;           // bf16 [6144][4096], dead after K3
    unsigned short* hfb   = (unsigned short*)d_out;           // bf16 [6144][2048]
    unsigned short* hcb   = ((unsigned short*)d_out) + 12582912;  // bf16 [6144][256]
    unsigned short* afcTb = ((unsigned short*)d_out) + 14155776;  // bf16 [256][2048]
    float* hf_out = out_f;
    float* hc_out = out_f + 12582912;
    float* hs_out = out_f + 14155776;

    // 1. xt = transpose(x)
    transpose_vl<<<dim3(VV / 128, NB * CC), 256, 0, stream>>>(x, xt);
    // 2. xc = xt @ afc  (fp32 - feeds the gram/threshold path)
    gemm_k<64, 64, 8, 4, 4, false, false, false><<<dim3(VCC / 64, MM / 64), 256, 0, stream>>>(
        xt, VV, afc, VCC, nullptr, 0, nullptr, xc, VCC, VV, 1.0f);
    // 3. single-pass fine chanmix: y0 -> hf (fp32), y12 -> d_out (bf16). xt dead after.
    chanmix_fine<<<dim3(96, 16), 256, 0, stream>>>(xt, W, hf, y12u);
    // 4. Bt = bf16 transpose of stacked [A1;A2] [4096][2048] -> [2048][4096] (into xt region)
    cvt_T_bf16_k<<<dim3(VV / 32, 2 * VV / 32), 256, 0, stream>>>(sup, Btu, 2 * VV, VV);
    // 5. afcb = bf16(afc)  [2048][256]
    cvt_bf16_k<<<dim3(512), 256, 0, stream>>>(afc, afcb, (long)VV * VCC);
    // 6. sxg = xc @ acs (fp32)
    gemm_k<64, 64, 8, 4, 4, false, false, false><<<dim3(1, MM / 64), 256, 0, stream>>>(
        xc, VCC, acs, SS, nullptr, 0, nullptr, sxg, SS, VCC, 1.0f);
    // 7. coarse chanmix
    chanmix_k<<<dim3(12, 16), 256, 0, stream>>>(xc, W, LL * VCC, VCC, yc0, yc12, 2 * VCC);
    // 8. super chanmix
    chanmix_k<<<dim3(3, 16), 256, 0, stream>>>(sxg, W, LL * SS, SS, ys0, ys12, 2 * SS);
    // 9. gram + supports
    zero_k<<<dim3(4), 256, 0, stream>>>(am, 4096);
    asmat_split<<<dim3(48), 256, 0, stream>>>(sxg, am);
    supbuild_k<<<dim3(1), 64, 0, stream>>>(am, sups);
    // 10. K3 (MFMA, fused both supports): hf = y0 + y12 @ [A1;A2] + bias  (K=4096)
    gemm_mfma<false, true><<<dim3(VV / 128, MM / 128), 256, 0, stream>>>(
        y12u, 4096, Btu, 4096, hf, VV, b, hf, VV, 4096, 1.0f);
    // 11. hc = yc0 + yc12 @ [Ac1;Ac2] + bias (fp32)
    gemm_k<64, 64, 8, 4, 4, false, true, true><<<dim3(VCC / 64, MM / 64), 256, 0, stream>>>(
        yc12, 2 * VCC, supc, VCC, yc0, VCC, b, hc, VCC, 2 * VCC, 1.0f);
    // 12. hs = ys0 + ys12 @ [As1;As2] + bias (fp32)
    gemm_k<64, 64, 8, 4, 4, false, true, true><<<dim3(1, MM / 64), 256, 0, stream>>>(
        ys12, 2 * SS, sups, SS, ys0, SS, b, hs, SS, 2 * SS, 1.0f);
    // 13. acsT (fp32, for K13)
    transpose2d<<<dim3(SS / 32, VCC / 32), 256, 0, stream>>>(acs, acsT, VCC, SS);
    // 14. K13: hc += 0.8 * relu(hs @ acs^T) (fp32, K=64)
    gemm_k<64, 64, 8, 4, 4, true, true, false><<<dim3(VCC / 64, MM / 64), 256, 0, stream>>>(
        hs, SS, acsT, VCC, hc, VCC, nullptr, hc, VCC, SS, 0.8f);
    // 15. hcb = bf16(hc)   (y12 dead after step 10)
    cvt_bf16_k<<<dim3(1536), 256, 0, stream>>>(hc, hcb, (long)MM * VCC);
    // 16. K14 (MFMA): hf += 0.2 * relu(hcb @ afc^T)   (B^T layout = afc itself)
    gemm_mfma<true, false><<<dim3(VV / 128, MM / 128), 256, 0, stream>>>(
        hcb, VCC, afcb, VCC, hf, VV, nullptr, hf, VV, VCC, 0.2f);
    // 17. hfb = bf16(hf)
    cvt_bf16_k<<<dim3(12288), 256, 0, stream>>>(hf, hfb, (long)MM * VV);
    // 18. afcTb = bf16 transpose of afc -> [256][2048]
    cvt_T_bf16_k<<<dim3(VCC / 32, VV / 32), 256, 0, stream>>>(afc, afcTb, VV, VCC);
    // 19. K15 (MFMA): hc += 0.2 * relu(hfb @ afc)   (B^T layout = afc^T = afcTb)
    gemm_mfma<true, false><<<dim3(VCC / 128, MM / 128), 256, 0, stream>>>(
        hfb, VV, afcTb, VV, hc, VCC, nullptr, hc, VCC, VV, 0.2f);
    // 20. K16: hs += 0.2 * relu(hc @ acs) (fp32, K=256)
    gemm_k<64, 64, 8, 4, 4, true, true, false><<<dim3(1, MM / 64), 256, 0, stream>>>(
        hc, VCC, acs, SS, hs, SS, nullptr, hs, SS, VCC, 0.2f);
    // 21. node-last -> reference layout [*, node, L]
    transpose_lv<<<dim3(VV / 128, NB * CO), 256, 0, stream>>>(hf, hf_out, VV, 128);
    transpose_lv<<<dim3(VCC / 128, NB * CO), 256, 0, stream>>>(hc, hc_out, VCC, 128);
    transpose_lv<<<dim3(1, NB * CO), 256, 0, stream>>>(hs, hs_out, SS, 64);
}

// Round 4
// 681.794 us; speedup vs baseline: 4.1390x; 1.2724x over previous
//
#include <hip/hip_runtime.h>

// ---------------- problem dims ----------------
constexpr int NB = 16;    // batch
constexpr int CC = 32;    // in channels
constexpr int VV = 2048;  // fine nodes
constexpr int VCC = 256;  // coarse nodes
constexpr int SS = 64;    // super nodes
constexpr int LL = 12;    // time
constexpr int CO = 32;    // out channels
constexpr long MM = (long)NB * CO * LL;  // 6144 rows in node-last layout

typedef __attribute__((ext_vector_type(8))) __bf16 bf16x8;
typedef __attribute__((ext_vector_type(4))) float f32x4;

__device__ __forceinline__ unsigned short f2bf(float f) {
    unsigned u = __float_as_uint(f);
    unsigned r = u + 0x7FFFu + ((u >> 16) & 1u);  // RNE
    return (unsigned short)(r >> 16);
}

__device__ __forceinline__ void gl_lds16(const void* g, void* l) {
    __builtin_amdgcn_global_load_lds(
        (const __attribute__((address_space(1))) void*)g,
        (__attribute__((address_space(3))) void*)l, 16, 0, 0);
}

// =====================================================================
// K1: x [nc, V, 12] -> xt fp32 [nc, 12, V] AND xtb bf16 (same layout)
__global__ __launch_bounds__(256)
void transpose_vl(const float* __restrict__ in, float* __restrict__ out,
                  unsigned short* __restrict__ outb) {
    __shared__ float t[128 * 12];
    const long nc = blockIdx.y;
    const int v0 = blockIdx.x * 128;
    const float* src = in + (nc * VV + v0) * 12;
    for (int f = threadIdx.x; f < 128 * 12; f += 256) t[f] = src[f];
    __syncthreads();
    float* dst = out + nc * 12L * VV;
    unsigned short* dstb = outb + nc * 12L * VV;
    for (int g = threadIdx.x; g < 128 * 12; g += 256) {
        int l = g >> 7, vv = g & 127;
        const float v = t[vv * 12 + l];
        dst[(long)l * VV + v0 + vv] = v;
        dstb[(long)l * VV + v0 + vv] = f2bf(v);
    }
}

// out-transpose: in [nc, 12, Kn] -> out [nc, Kn, 12]
__global__ __launch_bounds__(256)
void transpose_lv(const float* __restrict__ in, float* __restrict__ out, int Kn, int TW) {
    __shared__ float t[128 * 12];
    const long nc = blockIdx.y;
    const int v0 = blockIdx.x * TW;
    const float* src = in + nc * 12L * Kn;
    for (int g = threadIdx.x; g < TW * 12; g += 256) {
        int l = g / TW, vv = g - l * TW;
        t[vv * 12 + l] = src[(long)l * Kn + v0 + vv];
    }
    __syncthreads();
    float* dst = out + (nc * Kn + v0) * 12L;
    for (int f = threadIdx.x; f < TW * 12; f += 256) dst[f] = t[f];
}

// small dense fp32 transpose: in [rows, cols] -> out [cols, rows]
__global__ __launch_bounds__(256)
void transpose2d(const float* __restrict__ in, float* __restrict__ out, int rows, int cols) {
    __shared__ float t[32][33];
    const int r0 = blockIdx.y * 32, c0 = blockIdx.x * 32;
    const int ty = threadIdx.x / 32, tx = threadIdx.x % 32;
    for (int i = ty; i < 32; i += 8) t[i][tx] = in[(long)(r0 + i) * cols + c0 + tx];
    __syncthreads();
    for (int i = ty; i < 32; i += 8) out[(long)(c0 + i) * rows + r0 + tx] = t[tx][i];
}

// fp32 -> bf16 elementwise (n % 4 == 0)
__global__ __launch_bounds__(256)
void cvt_bf16_k(const float* __restrict__ in, unsigned short* __restrict__ out, long n) {
    long i = ((long)blockIdx.x * 256 + threadIdx.x) * 4;
    if (i >= n) return;
    const float4 v = *(const float4*)(in + i);
    ushort4 o;
    o.x = f2bf(v.x); o.y = f2bf(v.y); o.z = f2bf(v.z); o.w = f2bf(v.w);
    *(ushort4*)(out + i) = o;
}

// fp32 [R,C] -> bf16 transpose [C,R]
__global__ __launch_bounds__(256)
void cvt_T_bf16_k(const float* __restrict__ in, unsigned short* __restrict__ out,
                  int R, int Ccols) {
    __shared__ float t[32][33];
    const int r0 = blockIdx.y * 32, c0 = blockIdx.x * 32;
    const int ty = threadIdx.x / 32, tx = threadIdx.x % 32;
    for (int i = ty; i < 32; i += 8) t[i][tx] = in[(long)(r0 + i) * Ccols + c0 + tx];
    __syncthreads();
    for (int i = ty; i < 32; i += 8) out[(long)(c0 + i) * R + r0 + tx] = f2bf(t[tx][i]);
}

// =====================================================================
// fine channel mix: xt [16,32,24576] -> y0 fp32 [M,2048], y12 bf16 [M,4096]
__global__ __launch_bounds__(256)
void chanmix_fine(const float* __restrict__ in, const float* __restrict__ Wt,
                  float* __restrict__ y0, unsigned short* __restrict__ y12) {
    __shared__ float Ws[CO * 96];
    for (int idx = threadIdx.x; idx < CO * 96; idx += 256) Ws[idx] = Wt[idx];
    __syncthreads();
    const int nb = blockIdx.y;
    const int r = blockIdx.x * 256 + threadIdx.x;
    const int R = LL * VV;
    const int l = r / VV, k = r - l * VV;
    float xv[CC];
#pragma unroll
    for (int c = 0; c < CC; ++c) xv[c] = in[((long)(nb * CC + c)) * R + r];
    for (int o = 0; o < CO; ++o) {
        float a0 = 0.f, a1 = 0.f, a2 = 0.f;
#pragma unroll
        for (int c = 0; c < CC; ++c) {
            const float x = xv[c];
            a0 = fmaf(Ws[o * 96 + c], x, a0);
            a1 = fmaf(Ws[o * 96 + 32 + c], x, a1);
            a2 = fmaf(Ws[o * 96 + 64 + c], x, a2);
        }
        const long mrow = (long)(nb * CO + o) * LL + l;
        y0[mrow * VV + k] = a0;
        y12[mrow * 4096 + k] = f2bf(a1);
        y12[mrow * 4096 + 2048 + k] = f2bf(a2);
    }
}

// coarse/super channel mix (fp32 outputs)
__global__ __launch_bounds__(256)
void chanmix_k(const float* __restrict__ in, const float* __restrict__ Wt,
               int R, int Kn, float* __restrict__ o0,
               float* __restrict__ o1, int ld1) {
    __shared__ float Ws[CO * 96];
    for (int idx = threadIdx.x; idx < CO * 96; idx += 256) Ws[idx] = Wt[idx];
    __syncthreads();
    const int nb = blockIdx.y;
    const int r = blockIdx.x * 256 + threadIdx.x;
    if (r >= R) return;
    const int l = r / Kn, k = r - l * Kn;
    float xv[CC];
#pragma unroll
    for (int c = 0; c < CC; ++c) xv[c] = in[((long)(nb * CC + c)) * R + r];
    for (int o = 0; o < CO; ++o) {
        float a0 = 0.f, a1 = 0.f, a2 = 0.f;
#pragma unroll
        for (int c = 0; c < CC; ++c) {
            const float x = xv[c];
            a0 = fmaf(Ws[o * 96 + c], x, a0);
            a1 = fmaf(Ws[o * 96 + 32 + c], x, a1);
            a2 = fmaf(Ws[o * 96 + 64 + c], x, a2);
        }
        const long mrow = (long)(nb * CO + o) * LL + l;
        o0[mrow * Kn + k] = a0;
        o1[mrow * ld1 + k] = a1;
        o1[mrow * ld1 + Kn + k] = a2;
    }
}

// =====================================================================
// bf16 MFMA GEMM: Out[m,n] = (ADDC0? C0[m,n]:0) + (BIAS? bias[(m/12)&31]:0)
//                           + alpha * (RELU? relu(A@B) : A@B)
// A [M,K] bf16 row-major (lda), Bt [N,K] bf16 row-major (ldb)  (i.e. B^T).
// Tile 128x128, BK=64, 4 waves, 16x16x32 MFMA, XOR-swizzled LDS,
// global_load_lds width-16 staging. M%128==0, N%128==0, K%64==0.
template <bool RELU, bool ADDC0, bool BIAS>
__global__ __launch_bounds__(256)
void gemm_mfma(const unsigned short* __restrict__ A, int lda,
               const unsigned short* __restrict__ Bt, int ldb,
               const float* __restrict__ C0, int ldc,
               const float* __restrict__ bias,
               float* __restrict__ Out, int ldo, int K, float alpha) {
    __shared__ __align__(16) unsigned short As[128 * 64];
    __shared__ __align__(16) unsigned short Bs[128 * 64];
    const int tid = threadIdx.x;
    const int lane = tid & 63;
    const int w = tid >> 6;
    const long m0 = (long)blockIdx.y * 128;
    const int n0 = blockIdx.x * 128;

    long offA[4], offB[4];
#pragma unroll
    for (int q = 0; q < 4; ++q) {
        const int t = q * 256 + tid;
        const int row = t >> 3, pos = t & 7;
        const int lc = pos ^ (row & 7);
        offA[q] = (m0 + row) * (long)lda + lc * 8;
        offB[q] = (long)(n0 + row) * ldb + lc * 8;
    }
    const int wm = (w & 1) * 64, wn = (w >> 1) * 64;
    const int mrow = lane & 15;
    const int quad = lane >> 4;

    f32x4 acc[4][4];
#pragma unroll
    for (int i = 0; i < 4; ++i)
#pragma unroll
        for (int j = 0; j < 4; ++j) acc[i][j] = (f32x4){0.f, 0.f, 0.f, 0.f};

    for (int k0 = 0; k0 < K; k0 += 64) {
#pragma unroll
        for (int q = 0; q < 4; ++q)
            gl_lds16(A + offA[q] + k0, &As[(q * 256 + w * 64) * 8]);
#pragma unroll
        for (int q = 0; q < 4; ++q)
            gl_lds16(Bt + offB[q] + k0, &Bs[(q * 256 + w * 64) * 8]);
        __syncthreads();
#pragma unroll
        for (int ks = 0; ks < 2; ++ks) {
            bf16x8 af[4], bfr[4];
            const int pos = (ks * 4 + quad) ^ (mrow & 7);
#pragma unroll
            for (int tm = 0; tm < 4; ++tm) {
                const int r = wm + tm * 16 + mrow;
                af[tm] = *(const bf16x8*)&As[r * 64 + pos * 8];
            }
#pragma unroll
            for (int tn = 0; tn < 4; ++tn) {
                const int r = wn + tn * 16 + mrow;
                bfr[tn] = *(const bf16x8*)&Bs[r * 64 + pos * 8];
            }
#pragma unroll
            for (int tm = 0; tm < 4; ++tm)
#pragma unroll
                for (int tn = 0; tn < 4; ++tn)
                    acc[tm][tn] = __builtin_amdgcn_mfma_f32_16x16x32_bf16(
                        af[tm], bfr[tn], acc[tm][tn], 0, 0, 0);
        }
        __syncthreads();
    }

    // C/D layout: col = lane&15, row = quad*4 + reg
#pragma unroll
    for (int tm = 0; tm < 4; ++tm) {
#pragma unroll
        for (int tn = 0; tn < 4; ++tn) {
            const int n = n0 + wn + tn * 16 + mrow;
#pragma unroll
            for (int reg = 0; reg < 4; ++reg) {
                const long m = m0 + wm + tm * 16 + quad * 4 + reg;
                float p = acc[tm][tn][reg];
                if (RELU) p = fmaxf(p, 0.f);
                p *= alpha;
                float c = 0.f;
                if constexpr (ADDC0) c = C0[m * (long)ldc + n];
                if (BIAS) c += bias[(int)((m / LL) & (CO - 1))];
                Out[m * (long)ldo + n] = c + p;
            }
        }
    }
}

// =====================================================================
// generic fp32 GEMM (narrow / accuracy-critical ops)
template <int BM, int BN, int BK, int TM, int TN, bool RELU, bool ADDC0, bool BIAS>
__global__ __launch_bounds__(256)
void gemm_k(const float* __restrict__ X, int ldx,
            const float* __restrict__ Bm, int ldb,
            const float* __restrict__ C0, int ldc,
            const float* __restrict__ bias,
            float* __restrict__ Out, int ldo, int K, float alpha) {
    constexpr int TX = BN / TN;
    constexpr int LX = (BM * BK) / 256;
    constexpr int LB = (BN * BK) / 256;
    __shared__ float Xs[BK][BM + 4];
    __shared__ float Bs[BK][BN + 4];
    const int tid = threadIdx.x;
    const int tx = tid % TX, ty = tid / TX;
    const long m0 = (long)blockIdx.y * BM;
    const int n0 = blockIdx.x * BN;
    const int xr = tid / (BK / LX);
    const int xcc = (tid % (BK / LX)) * LX;
    const int br = tid / (BN / LB);
    const int bc = (tid % (BN / LB)) * LB;

    float acc[TM][TN];
#pragma unroll
    for (int i = 0; i < TM; ++i)
#pragma unroll
        for (int j = 0; j < TN; ++j) acc[i][j] = 0.f;

    const float* Xp = X + (m0 + xr) * (long)ldx + xcc;
    const float* Bp = Bm + (long)br * ldb + n0 + bc;

    for (int k0 = 0; k0 < K; k0 += BK) {
        if constexpr (LX == 4) {
            const float4 v = *(const float4*)Xp;
            Xs[xcc + 0][xr] = v.x; Xs[xcc + 1][xr] = v.y;
            Xs[xcc + 2][xr] = v.z; Xs[xcc + 3][xr] = v.w;
        } else {
            const float2 v = *(const float2*)Xp;
            Xs[xcc + 0][xr] = v.x; Xs[xcc + 1][xr] = v.y;
        }
        if constexpr (LB == 4) {
            *(float4*)&Bs[br][bc] = *(const float4*)Bp;
        } else {
            *(float2*)&Bs[br][bc] = *(const float2*)Bp;
        }
        __syncthreads();
#pragma unroll
        for (int kk = 0; kk < BK; ++kk) {
            float a[TM], b[TN];
#pragma unroll
            for (int i = 0; i < TM; ++i) a[i] = Xs[kk][ty * TM + i];
#pragma unroll
            for (int j = 0; j < TN; ++j) b[j] = Bs[kk][tx * TN + j];
#pragma unroll
            for (int i = 0; i < TM; ++i)
#pragma unroll
                for (int j = 0; j < TN; ++j) acc[i][j] = fmaf(a[i], b[j], acc[i][j]);
        }
        __syncthreads();
        Xp += BK;
        Bp += (long)BK * ldb;
    }

#pragma unroll
    for (int i = 0; i < TM; ++i) {
        const long m = m0 + (long)ty * TM + i;
        float bv = 0.f;
        if (BIAS) bv = bias[(int)((m / LL) & (CO - 1))];
        const long obase = m * (long)ldo + n0 + tx * TN;
        long cbase = 0;
        if constexpr (ADDC0) cbase = m * (long)ldc + n0 + tx * TN;
#pragma unroll
        for (int j = 0; j < TN; ++j) {
            float p = acc[i][j];
            if (RELU) p = fmaxf(p, 0.f);
            p *= alpha;
            float c = 0.f;
            if constexpr (ADDC0) c = C0[cbase + j];
            Out[obase + j] = c + p + bv;
        }
    }
}

// =====================================================================
__global__ __launch_bounds__(256)
void zero_k(float* __restrict__ p, int n) {
    for (int i = blockIdx.x * 256 + threadIdx.x; i < n; i += gridDim.x * 256) p[i] = 0.f;
}

// split-K Gram with mismatched flatten orders (faithful)
__global__ __launch_bounds__(256)
void asmat_split(const float* __restrict__ sxg, float* __restrict__ am_raw) {
    __shared__ float Us[128][65];
    __shared__ float Wsh[128][65];
    __shared__ int rA[128], rB[128];
    const int i0 = blockIdx.x * 128;
    const int tid = threadIdx.x;
    if (tid < 128) {
        const int i = i0 + tid;
        const int c = i / 192;
        const int rem = i - c * 192;
        const int n = rem / 12;
        const int l = rem - n * 12;
        rA[tid] = (n * 32 + c) * 12 + l;
        const int l2 = i >> 9;
        const int rem2 = i & 511;
        rB[tid] = ((rem2 >> 5) * 32 + (rem2 & 31)) * 12 + l2;
    }
    __syncthreads();
    for (int idx = tid; idx < 128 * 64; idx += 256) {
        const int r = idx >> 6, s = idx & 63;
        Us[r][s] = sxg[rA[r] * 64 + s];
        Wsh[r][s] = sxg[rB[r] * 64 + s];
    }
    __syncthreads();
    const int ts = (tid & 15) * 4;
    const int tt = (tid >> 4) * 4;
    float acc[4][4];
#pragma unroll
    for (int i2 = 0; i2 < 4; ++i2)
#pragma unroll
        for (int j = 0; j < 4; ++j) acc[i2][j] = 0.f;
    for (int k = 0; k < 128; ++k) {
        float a[4], bv[4];
#pragma unroll
        for (int i2 = 0; i2 < 4; ++i2) a[i2] = Us[k][ts + i2];
#pragma unroll
        for (int j = 0; j < 4; ++j) bv[j] = Wsh[k][tt + j];
#pragma unroll
        for (int i2 = 0; i2 < 4; ++i2)
#pragma unroll
            for (int j = 0; j < 4; ++j) acc[i2][j] = fmaf(a[i2], bv[j], acc[i2][j]);
    }
#pragma unroll
    for (int i2 = 0; i2 < 4; ++i2)
#pragma unroll
        for (int j = 0; j < 4; ++j)
            atomicAdd(&am_raw[(ts + i2) * 64 + tt + j], acc[i2][j]);
}

// sup[0] = softmax(rownorm(relu(raw-0.5))), sup[1] = same on transpose
__global__ __launch_bounds__(64)
void supbuild_k(const float* __restrict__ am_raw, float* __restrict__ sup) {
    __shared__ float a[64][65];
    for (int idx = threadIdx.x; idx < 4096; idx += 64) {
        const float v = am_raw[idx] - 0.5f;
        a[idx >> 6][idx & 63] = v > 0.f ? v : 0.f;
    }
    __syncthreads();
    const int r = threadIdx.x;
    {
        float rs = 0.f;
        for (int j = 0; j < 64; ++j) rs += a[r][j];
        const float dinv = rs > 0.f ? 1.f / rs : 0.f;
        float mx = -1e30f;
        for (int j = 0; j < 64; ++j) mx = fmaxf(mx, a[r][j] * dinv);
        float se = 0.f;
        for (int j = 0; j < 64; ++j) se += expf(a[r][j] * dinv - mx);
        const float inv = 1.f / se;
        for (int j = 0; j < 64; ++j) sup[r * 64 + j] = expf(a[r][j] * dinv - mx) * inv;
    }
    {
        float rs = 0.f;
        for (int j = 0; j < 64; ++j) rs += a[j][r];
        const float dinv = rs > 0.f ? 1.f / rs : 0.f;
        float mx = -1e30f;
        for (int j = 0; j < 64; ++j) mx = fmaxf(mx, a[j][r] * dinv);
        float se = 0.f;
        for (int j = 0; j < 64; ++j) se += expf(a[j][r] * dinv - mx);
        const float inv = 1.f / se;
        for (int j = 0; j < 64; ++j) sup[4096 + r * 64 + j] = expf(a[j][r] * dinv - mx) * inv;
    }
}

// =====================================================================
extern "C" void kernel_launch(void* const* d_in, const int* in_sizes, int n_in,
                              void* d_out, int out_size, void* d_ws, size_t ws_size,
                              hipStream_t stream) {
    (void)in_sizes; (void)n_in; (void)out_size; (void)ws_size;
    const float* x    = (const float*)d_in[0];
    const float* sup  = (const float*)d_in[1];  // [2, V, V]
    const float* supc = (const float*)d_in[2];  // [2, VC, VC]
    const float* acs  = (const float*)d_in[3];  // [VC, S]
    const float* afc  = (const float*)d_in[4];  // [V, VC]
    const float* W    = (const float*)d_in[5];  // [32, 96]
    const float* b    = (const float*)d_in[6];  // [32]
    float* ws = (float*)d_ws;

    // --- region A [0, 12,582,912): xt fp32 (alive steps 1-4); then reused:
    float* xt = ws;
    unsigned short* Btu  = (unsigned short*)ws;               // bf16 [2048][4096]
    unsigned short* afcb = (unsigned short*)(ws + 4194304);   // bf16 [2048][256] (B^T for K14)
    float* yc0  = ws + 4456448;
    float* yc12 = ws + 6029312;
    float* ys0  = ws + 9175040;
    float* ys12 = ws + 9568256;
    float* hc   = ws + 10354688;
    float* hs   = ws + 11927552;
    float* am   = ws + 12320768;
    float* sups = ws + 12324864;
    float* acsT = ws + 12333056;                              // ends 12,349,440
    // --- fixed regions
    float* hf   = ws + 12582912;                              // y0 then hf
    float* xc   = ws + 25165824;
    float* sxg  = ws + 26738688;
    unsigned short* afcTb = (unsigned short*)(ws + 27131904); // bf16 [256][2048], alive all session
    // ws total 27,394,048 floats (~110 MB)

    // --- d_out doubles as scratch (dead before final output writes)
    float* out_f = (float*)d_out;
    unsigned short* xtb  = (unsigned short*)d_out;            // bf16 [6144][2048], steps 1-3
    unsigned short* y12u = (unsigned short*)d_out;            // bf16 [6144][4096], steps 4-11
    unsigned short* hfb  = (unsigned short*)d_out;            // bf16 [6144][2048]
    unsigned short* hcb  = ((unsigned short*)d_out) + 12582912;  // bf16 [6144][256]
    float* hf_out = out_f;
    float* hc_out = out_f + 12582912;
    float* hs_out = out_f + 14155776;

    // 1. xt = transpose(x) (+ bf16 copy xtb into d_out)
    transpose_vl<<<dim3(VV / 128, NB * CC), 256, 0, stream>>>(x, xt, xtb);
    // 2. afcTb = bf16(afc^T) [256][2048]  (ws tail; needed now and at step 19)
    cvt_T_bf16_k<<<dim3(VCC / 32, VV / 32), 256, 0, stream>>>(afc, afcTb, VV, VCC);
    // 3. xc = xtb @ afc  (MFMA; B^T = afcTb)  grid (2,48)
    gemm_mfma<false, false, false><<<dim3(VCC / 128, MM / 128), 256, 0, stream>>>(
        xtb, VV, afcTb, VV, nullptr, 0, nullptr, xc, VCC, VV, 1.0f);
    // 4. fine chanmix: y0 -> hf (fp32), y12 -> d_out (bf16; clobbers xtb - dead)
    chanmix_fine<<<dim3(96, 16), 256, 0, stream>>>(xt, W, hf, y12u);
    // 5. Btu = bf16([A1;A2]^T) [2048][4096]  (region A; xt dead after step 4)
    cvt_T_bf16_k<<<dim3(VV / 32, 2 * VV / 32), 256, 0, stream>>>(sup, Btu, 2 * VV, VV);
    // 6. afcb = bf16(afc) [2048][256]
    cvt_bf16_k<<<dim3(512), 256, 0, stream>>>(afc, afcb, (long)VV * VCC);
    // 7. sxg = xc @ acs (fp32, BK=16)
    gemm_k<64, 64, 16, 4, 4, false, false, false><<<dim3(1, MM / 64), 256, 0, stream>>>(
        xc, VCC, acs, SS, nullptr, 0, nullptr, sxg, SS, VCC, 1.0f);
    // 8. coarse chanmix
    chanmix_k<<<dim3(12, 16), 256, 0, stream>>>(xc, W, LL * VCC, VCC, yc0, yc12, 2 * VCC);
    // 9. super chanmix
    chanmix_k<<<dim3(3, 16), 256, 0, stream>>>(sxg, W, LL * SS, SS, ys0, ys12, 2 * SS);
    // 10. gram + supports
    zero_k<<<dim3(4), 256, 0, stream>>>(am, 4096);
    asmat_split<<<dim3(48), 256, 0, stream>>>(sxg, am);
    supbuild_k<<<dim3(1), 64, 0, stream>>>(am, sups);
    // 11. K3 (MFMA, fused supports): hf = y0 + y12 @ [A1;A2] + bias  (K=4096)
    gemm_mfma<false, true, true><<<dim3(VV / 128, MM / 128), 256, 0, stream>>>(
        y12u, 4096, Btu, 4096, hf, VV, b, hf, VV, 4096, 1.0f);
    // 12. hc = yc0 + yc12 @ [Ac1;Ac2] + bias (fp32, BK=16)
    gemm_k<64, 64, 16, 4, 4, false, true, true><<<dim3(VCC / 64, MM / 64), 256, 0, stream>>>(
        yc12, 2 * VCC, supc, VCC, yc0, VCC, b, hc, VCC, 2 * VCC, 1.0f);
    // 13. hs = ys0 + ys12 @ [As1;As2] + bias (fp32, BK=16, K=128)
    gemm_k<64, 64, 16, 4, 4, false, true, true><<<dim3(1, MM / 64), 256, 0, stream>>>(
        ys12, 2 * SS, sups, SS, ys0, SS, b, hs, SS, 2 * SS, 1.0f);
    // 14. acsT (fp32)
    transpose2d<<<dim3(SS / 32, VCC / 32), 256, 0, stream>>>(acs, acsT, VCC, SS);
    // 15. hc += 0.8 * relu(hs @ acs^T) (fp32, BK=16, K=64)
    gemm_k<64, 64, 16, 4, 4, true, true, false><<<dim3(VCC / 64, MM / 64), 256, 0, stream>>>(
        hs, SS, acsT, VCC, hc, VCC, nullptr, hc, VCC, SS, 0.8f);
    // 16. hcb = bf16(hc)  (y12 dead after step 11)
    cvt_bf16_k<<<dim3(1536), 256, 0, stream>>>(hc, hcb, (long)MM * VCC);
    // 17. K14 (MFMA): hf += 0.2 * relu(hcb @ afc^T)  (B^T = afc = afcb)
    gemm_mfma<true, true, false><<<dim3(VV / 128, MM / 128), 256, 0, stream>>>(
        hcb, VCC, afcb, VCC, hf, VV, nullptr, hf, VV, VCC, 0.2f);
    // 18. hfb = bf16(hf)
    cvt_bf16_k<<<dim3(12288), 256, 0, stream>>>(hf, hfb, (long)MM * VV);
    // 19. K15 (MFMA): hc += 0.2 * relu(hfb @ afc)  (B^T = afc^T = afcTb)
    gemm_mfma<true, true, false><<<dim3(VCC / 128, MM / 128), 256, 0, stream>>>(
        hfb, VV, afcTb, VV, hc, VCC, nullptr, hc, VCC, VV, 0.2f);
    // 20. hs += 0.2 * relu(hc @ acs) (fp32, BK=16, K=256)
    gemm_k<64, 64, 16, 4, 4, true, true, false><<<dim3(1, MM / 64), 256, 0, stream>>>(
        hc, VCC, acs, SS, hs, SS, nullptr, hs, SS, VCC, 0.2f);
    // 21. node-last -> reference layout [*, node, L]
    transpose_lv<<<dim3(VV / 128, NB * CO), 256, 0, stream>>>(hf, hf_out, VV, 128);
    transpose_lv<<<dim3(VCC / 128, NB * CO), 256, 0, stream>>>(hc, hc_out, VCC, 128);
    transpose_lv<<<dim3(1, NB * CO), 256, 0, stream>>>(hs, hs_out, SS, 64);
}

// Round 5
// 645.943 us; speedup vs baseline: 4.3687x; 1.0555x over previous
//
#include <hip/hip_runtime.h>

// ---------------- problem dims ----------------
constexpr int NB = 16;    // batch
constexpr int CC = 32;    // in channels
constexpr int VV = 2048;  // fine nodes
constexpr int VCC = 256;  // coarse nodes
constexpr int SS = 64;    // super nodes
constexpr int LL = 12;    // time
constexpr int CO = 32;    // out channels
constexpr long MM = (long)NB * CO * LL;  // 6144 rows in node-last layout

typedef __attribute__((ext_vector_type(8))) __bf16 bf16x8;
typedef __attribute__((ext_vector_type(4))) float f32x4;

__device__ __forceinline__ unsigned short f2bf(float f) {
    unsigned u = __float_as_uint(f);
    unsigned r = u + 0x7FFFu + ((u >> 16) & 1u);  // RNE
    return (unsigned short)(r >> 16);
}

__device__ __forceinline__ void gl_lds16(const void* g, void* l) {
    __builtin_amdgcn_global_load_lds(
        (const __attribute__((address_space(1))) void*)g,
        (__attribute__((address_space(3))) void*)l, 16, 0, 0);
}

// =====================================================================
// K1: x [nc, V, 12] -> xt fp32 [nc, 12, V] AND xtb bf16 (same layout)
__global__ __launch_bounds__(256)
void transpose_vl(const float* __restrict__ in, float* __restrict__ out,
                  unsigned short* __restrict__ outb) {
    __shared__ float t[128 * 12];
    const long nc = blockIdx.y;
    const int v0 = blockIdx.x * 128;
    const float* src = in + (nc * VV + v0) * 12;
    for (int f = threadIdx.x; f < 128 * 12; f += 256) t[f] = src[f];
    __syncthreads();
    float* dst = out + nc * 12L * VV;
    unsigned short* dstb = outb + nc * 12L * VV;
    for (int g = threadIdx.x; g < 128 * 12; g += 256) {
        int l = g >> 7, vv = g & 127;
        const float v = t[vv * 12 + l];
        dst[(long)l * VV + v0 + vv] = v;
        dstb[(long)l * VV + v0 + vv] = f2bf(v);
    }
}

// out-transpose: in [nc, 12, Kn] -> out [nc, Kn, 12]
__global__ __launch_bounds__(256)
void transpose_lv(const float* __restrict__ in, float* __restrict__ out, int Kn, int TW) {
    __shared__ float t[128 * 12];
    const long nc = blockIdx.y;
    const int v0 = blockIdx.x * TW;
    const float* src = in + nc * 12L * Kn;
    for (int g = threadIdx.x; g < TW * 12; g += 256) {
        int l = g / TW, vv = g - l * TW;
        t[vv * 12 + l] = src[(long)l * Kn + v0 + vv];
    }
    __syncthreads();
    float* dst = out + (nc * Kn + v0) * 12L;
    for (int f = threadIdx.x; f < TW * 12; f += 256) dst[f] = t[f];
}

// small dense fp32 transpose: in [rows, cols] -> out [cols, rows]
__global__ __launch_bounds__(256)
void transpose2d(const float* __restrict__ in, float* __restrict__ out, int rows, int cols) {
    __shared__ float t[32][33];
    const int r0 = blockIdx.y * 32, c0 = blockIdx.x * 32;
    const int ty = threadIdx.x / 32, tx = threadIdx.x % 32;
    for (int i = ty; i < 32; i += 8) t[i][tx] = in[(long)(r0 + i) * cols + c0 + tx];
    __syncthreads();
    for (int i = ty; i < 32; i += 8) out[(long)(c0 + i) * rows + r0 + tx] = t[tx][i];
}

// fp32 [R,C] -> bf16 transpose [C,R]
__global__ __launch_bounds__(256)
void cvt_T_bf16_k(const float* __restrict__ in, unsigned short* __restrict__ out,
                  int R, int Ccols) {
    __shared__ float t[32][33];
    const int r0 = blockIdx.y * 32, c0 = blockIdx.x * 32;
    const int ty = threadIdx.x / 32, tx = threadIdx.x % 32;
    for (int i = ty; i < 32; i += 8) t[i][tx] = in[(long)(r0 + i) * Ccols + c0 + tx];
    __syncthreads();
    for (int i = ty; i < 32; i += 8) out[(long)(c0 + i) * R + r0 + tx] = f2bf(t[tx][i]);
}

// afc [2048,256] fp32 -> afcb bf16 [2048,256] AND afcTb bf16 [256,2048]
__global__ __launch_bounds__(256)
void cvt_afc_both(const float* __restrict__ in, unsigned short* __restrict__ outn,
                  unsigned short* __restrict__ outt) {
    __shared__ float t[32][33];
    const int r0 = blockIdx.y * 32, c0 = blockIdx.x * 32;
    const int ty = threadIdx.x / 32, tx = threadIdx.x % 32;
    for (int i = ty; i < 32; i += 8) {
        const float v = in[(long)(r0 + i) * VCC + c0 + tx];
        t[i][tx] = v;
        outn[(long)(r0 + i) * VCC + c0 + tx] = f2bf(v);
    }
    __syncthreads();
    for (int i = ty; i < 32; i += 8) out_store:
        outt[(long)(c0 + i) * VV + r0 + tx] = f2bf(t[tx][i]);
}

// =====================================================================
// fine channel mix: xt [16,32,24576] -> y0 fp32 [M,2048], y12 bf16 [M,4096]
__global__ __launch_bounds__(256)
void chanmix_fine(const float* __restrict__ in, const float* __restrict__ Wt,
                  float* __restrict__ y0, unsigned short* __restrict__ y12) {
    __shared__ float Ws[CO * 96];
    for (int idx = threadIdx.x; idx < CO * 96; idx += 256) Ws[idx] = Wt[idx];
    __syncthreads();
    const int nb = blockIdx.y;
    const int r = blockIdx.x * 256 + threadIdx.x;
    const int R = LL * VV;
    const int l = r / VV, k = r - l * VV;
    float xv[CC];
#pragma unroll
    for (int c = 0; c < CC; ++c) xv[c] = in[((long)(nb * CC + c)) * R + r];
    for (int o = 0; o < CO; ++o) {
        float a0 = 0.f, a1 = 0.f, a2 = 0.f;
#pragma unroll
        for (int c = 0; c < CC; ++c) {
            const float x = xv[c];
            a0 = fmaf(Ws[o * 96 + c], x, a0);
            a1 = fmaf(Ws[o * 96 + 32 + c], x, a1);
            a2 = fmaf(Ws[o * 96 + 64 + c], x, a2);
        }
        const long mrow = (long)(nb * CO + o) * LL + l;
        y0[mrow * VV + k] = a0;
        y12[mrow * 4096 + k] = f2bf(a1);
        y12[mrow * 4096 + 2048 + k] = f2bf(a2);
    }
}

// coarse/super channel mix (fp32 outputs)
__global__ __launch_bounds__(256)
void chanmix_k(const float* __restrict__ in, const float* __restrict__ Wt,
               int R, int Kn, float* __restrict__ o0,
               float* __restrict__ o1, int ld1) {
    __shared__ float Ws[CO * 96];
    for (int idx = threadIdx.x; idx < CO * 96; idx += 256) Ws[idx] = Wt[idx];
    __syncthreads();
    const int nb = blockIdx.y;
    const int r = blockIdx.x * 256 + threadIdx.x;
    if (r >= R) return;
    const int l = r / Kn, k = r - l * Kn;
    float xv[CC];
#pragma unroll
    for (int c = 0; c < CC; ++c) xv[c] = in[((long)(nb * CC + c)) * R + r];
    for (int o = 0; o < CO; ++o) {
        float a0 = 0.f, a1 = 0.f, a2 = 0.f;
#pragma unroll
        for (int c = 0; c < CC; ++c) {
            const float x = xv[c];
            a0 = fmaf(Ws[o * 96 + c], x, a0);
            a1 = fmaf(Ws[o * 96 + 32 + c], x, a1);
            a2 = fmaf(Ws[o * 96 + 64 + c], x, a2);
        }
        const long mrow = (long)(nb * CO + o) * LL + l;
        o0[mrow * Kn + k] = a0;
        o1[mrow * ld1 + k] = a1;
        o1[mrow * ld1 + Kn + k] = a2;
    }
}

// =====================================================================
// bf16 MFMA GEMM: Out[m,n] = (ADDC0? C0[m,n]:0) + (BIAS? bias[(m/12)&31]:0)
//                           + alpha * (RELU? relu(A@B) : A@B)
// A [M,K] bf16 (lda), Bt [N,K] bf16 (ldb) (= B^T). Tile 128xBN, BK=64,
// 4 waves, 16x16x32 MFMA, XOR-swizzled LDS, global_load_lds width-16.
// SWIZ: GROUP_M=8 cutlass swizzle (requires gridDim.y % 8 == 0).
// STB16: also store bf16 copy of result to OutB (same [m,n], ld = ldo).
template <int BN, bool SWIZ, bool RELU, bool ADDC0, bool BIAS, bool STB16>
__global__ __launch_bounds__(256)
void gemm_mfma(const unsigned short* __restrict__ A, int lda,
               const unsigned short* __restrict__ Bt, int ldb,
               const float* __restrict__ C0, int ldc,
               const float* __restrict__ bias,
               float* __restrict__ Out, int ldo,
               unsigned short* __restrict__ OutB, int K, float alpha) {
    constexpr int TNT = BN / 32;   // 16-tiles per wave along n (4 or 2)
    constexpr int QB = BN / 32;    // B staging iters (4 or 2)
    constexpr int WN = BN / 2;     // wave n-extent
    __shared__ __align__(16) unsigned short As[128 * 64];
    __shared__ __align__(16) unsigned short Bs[BN * 64];
    const int tid = threadIdx.x;
    const int lane = tid & 63;
    const int w = tid >> 6;

    int pid_m, pid_n;
    if constexpr (SWIZ) {
        const int id = blockIdx.y * gridDim.x + blockIdx.x;
        const int npg = 8 * gridDim.x;
        const int rem = id % npg;
        pid_m = (id / npg) * 8 + (rem & 7);
        pid_n = rem >> 3;
    } else {
        pid_m = blockIdx.y;
        pid_n = blockIdx.x;
    }
    const long m0 = (long)pid_m * 128;
    const int n0 = pid_n * BN;

    long offA[4], offB[QB];
#pragma unroll
    for (int q = 0; q < 4; ++q) {
        const int t = q * 256 + tid;
        const int row = t >> 3, pos = t & 7;
        const int lc = pos ^ (row & 7);
        offA[q] = (m0 + row) * (long)lda + lc * 8;
    }
#pragma unroll
    for (int q = 0; q < QB; ++q) {
        const int t = q * 256 + tid;
        const int row = t >> 3, pos = t & 7;
        const int lc = pos ^ (row & 7);
        offB[q] = (long)(n0 + row) * ldb + lc * 8;
    }
    const int wm = (w & 1) * 64, wn = (w >> 1) * WN;
    const int mrow = lane & 15;
    const int quad = lane >> 4;

    f32x4 acc[4][TNT];
#pragma unroll
    for (int i = 0; i < 4; ++i)
#pragma unroll
        for (int j = 0; j < TNT; ++j) acc[i][j] = (f32x4){0.f, 0.f, 0.f, 0.f};

    for (int k0 = 0; k0 < K; k0 += 64) {
#pragma unroll
        for (int q = 0; q < 4; ++q)
            gl_lds16(A + offA[q] + k0, &As[(q * 256 + w * 64) * 8]);
#pragma unroll
        for (int q = 0; q < QB; ++q)
            gl_lds16(Bt + offB[q] + k0, &Bs[(q * 256 + w * 64) * 8]);
        __syncthreads();
#pragma unroll
        for (int ks = 0; ks < 2; ++ks) {
            bf16x8 af[4], bfr[TNT];
            const int pos = (ks * 4 + quad) ^ (mrow & 7);
#pragma unroll
            for (int tm = 0; tm < 4; ++tm) {
                const int r = wm + tm * 16 + mrow;
                af[tm] = *(const bf16x8*)&As[r * 64 + pos * 8];
            }
#pragma unroll
            for (int tn = 0; tn < TNT; ++tn) {
                const int r = wn + tn * 16 + mrow;
                bfr[tn] = *(const bf16x8*)&Bs[r * 64 + pos * 8];
            }
#pragma unroll
            for (int tm = 0; tm < 4; ++tm)
#pragma unroll
                for (int tn = 0; tn < TNT; ++tn)
                    acc[tm][tn] = __builtin_amdgcn_mfma_f32_16x16x32_bf16(
                        af[tm], bfr[tn], acc[tm][tn], 0, 0, 0);
        }
        __syncthreads();
    }

    // C/D layout: col = lane&15, row = quad*4 + reg
#pragma unroll
    for (int tm = 0; tm < 4; ++tm) {
#pragma unroll
        for (int tn = 0; tn < TNT; ++tn) {
            const int n = n0 + wn + tn * 16 + mrow;
#pragma unroll
            for (int reg = 0; reg < 4; ++reg) {
                const long m = m0 + wm + tm * 16 + quad * 4 + reg;
                float p = acc[tm][tn][reg];
                if (RELU) p = fmaxf(p, 0.f);
                p *= alpha;
                float c = 0.f;
                if constexpr (ADDC0) c = C0[m * (long)ldc + n];
                if (BIAS) c += bias[(int)((m / LL) & (CO - 1))];
                const float res = c + p;
                Out[m * (long)ldo + n] = res;
                if constexpr (STB16) OutB[m * (long)ldo + n] = f2bf(res);
            }
        }
    }
}

// =====================================================================
// generic fp32 GEMM (narrow / accuracy-critical ops); optional bf16 dual store
template <int BM, int BN, int BK, int TM, int TN, bool RELU, bool ADDC0, bool BIAS, bool STB16>
__global__ __launch_bounds__(256)
void gemm_k(const float* __restrict__ X, int ldx,
            const float* __restrict__ Bm, int ldb,
            const float* __restrict__ C0, int ldc,
            const float* __restrict__ bias,
            float* __restrict__ Out, int ldo,
            unsigned short* __restrict__ outb, int K, float alpha) {
    constexpr int TX = BN / TN;
    constexpr int LX = (BM * BK) / 256;
    constexpr int LB = (BN * BK) / 256;
    __shared__ float Xs[BK][BM + 4];
    __shared__ float Bs[BK][BN + 4];
    const int tid = threadIdx.x;
    const int tx = tid % TX, ty = tid / TX;
    const long m0 = (long)blockIdx.y * BM;
    const int n0 = blockIdx.x * BN;
    const int xr = tid / (BK / LX);
    const int xcc = (tid % (BK / LX)) * LX;
    const int br = tid / (BN / LB);
    const int bc = (tid % (BN / LB)) * LB;

    float acc[TM][TN];
#pragma unroll
    for (int i = 0; i < TM; ++i)
#pragma unroll
        for (int j = 0; j < TN; ++j) acc[i][j] = 0.f;

    const float* Xp = X + (m0 + xr) * (long)ldx + xcc;
    const float* Bp = Bm + (long)br * ldb + n0 + bc;

    for (int k0 = 0; k0 < K; k0 += BK) {
        if constexpr (LX == 4) {
            const float4 v = *(const float4*)Xp;
            Xs[xcc + 0][xr] = v.x; Xs[xcc + 1][xr] = v.y;
            Xs[xcc + 2][xr] = v.z; Xs[xcc + 3][xr] = v.w;
        } else {
            const float2 v = *(const float2*)Xp;
            Xs[xcc + 0][xr] = v.x; Xs[xcc + 1][xr] = v.y;
        }
        if constexpr (LB == 4) {
            *(float4*)&Bs[br][bc] = *(const float4*)Bp;
        } else {
            *(float2*)&Bs[br][bc] = *(const float2*)Bp;
        }
        __syncthreads();
#pragma unroll
        for (int kk = 0; kk < BK; ++kk) {
            float a[TM], b[TN];
#pragma unroll
            for (int i = 0; i < TM; ++i) a[i] = Xs[kk][ty * TM + i];
#pragma unroll
            for (int j = 0; j < TN; ++j) b[j] = Bs[kk][tx * TN + j];
#pragma unroll
            for (int i = 0; i < TM; ++i)
#pragma unroll
                for (int j = 0; j < TN; ++j) acc[i][j] = fmaf(a[i], b[j], acc[i][j]);
        }
        __syncthreads();
        Xp += BK;
        Bp += (long)BK * ldb;
    }

#pragma unroll
    for (int i = 0; i < TM; ++i) {
        const long m = m0 + (long)ty * TM + i;
        float bv = 0.f;
        if (BIAS) bv = bias[(int)((m / LL) & (CO - 1))];
        const long obase = m * (long)ldo + n0 + tx * TN;
        long cbase = 0;
        if constexpr (ADDC0) cbase = m * (long)ldc + n0 + tx * TN;
#pragma unroll
        for (int j = 0; j < TN; ++j) {
            float p = acc[i][j];
            if (RELU) p = fmaxf(p, 0.f);
            p *= alpha;
            float c = 0.f;
            if constexpr (ADDC0) c = C0[cbase + j];
            const float res = c + p + bv;
            Out[obase + j] = res;
            if constexpr (STB16) outb[obase + j] = f2bf(res);
        }
    }
}

// =====================================================================
__global__ __launch_bounds__(256)
void zero_k(float* __restrict__ p, int n) {
    for (int i = blockIdx.x * 256 + threadIdx.x; i < n; i += gridDim.x * 256) p[i] = 0.f;
}

// split-K Gram with mismatched flatten orders (faithful)
__global__ __launch_bounds__(256)
void asmat_split(const float* __restrict__ sxg, float* __restrict__ am_raw) {
    __shared__ float Us[128][65];
    __shared__ float Wsh[128][65];
    __shared__ int rA[128], rB[128];
    const int i0 = blockIdx.x * 128;
    const int tid = threadIdx.x;
    if (tid < 128) {
        const int i = i0 + tid;
        const int c = i / 192;
        const int rem = i - c * 192;
        const int n = rem / 12;
        const int l = rem - n * 12;
        rA[tid] = (n * 32 + c) * 12 + l;
        const int l2 = i >> 9;
        const int rem2 = i & 511;
        rB[tid] = ((rem2 >> 5) * 32 + (rem2 & 31)) * 12 + l2;
    }
    __syncthreads();
    for (int idx = tid; idx < 128 * 64; idx += 256) {
        const int r = idx >> 6, s = idx & 63;
        Us[r][s] = sxg[rA[r] * 64 + s];
        Wsh[r][s] = sxg[rB[r] * 64 + s];
    }
    __syncthreads();
    const int ts = (tid & 15) * 4;
    const int tt = (tid >> 4) * 4;
    float acc[4][4];
#pragma unroll
    for (int i2 = 0; i2 < 4; ++i2)
#pragma unroll
        for (int j = 0; j < 4; ++j) acc[i2][j] = 0.f;
    for (int k = 0; k < 128; ++k) {
        float a[4], bv[4];
#pragma unroll
        for (int i2 = 0; i2 < 4; ++i2) a[i2] = Us[k][ts + i2];
#pragma unroll
        for (int j = 0; j < 4; ++j) bv[j] = Wsh[k][tt + j];
#pragma unroll
        for (int i2 = 0; i2 < 4; ++i2)
#pragma unroll
            for (int j = 0; j < 4; ++j) acc[i2][j] = fmaf(a[i2], bv[j], acc[i2][j]);
    }
#pragma unroll
    for (int i2 = 0; i2 < 4; ++i2)
#pragma unroll
        for (int j = 0; j < 4; ++j)
            atomicAdd(&am_raw[(ts + i2) * 64 + tt + j], acc[i2][j]);
}

// sup[0] = softmax(rownorm(relu(raw-0.5))), sup[1] = same on transpose
__global__ __launch_bounds__(64)
void supbuild_k(const float* __restrict__ am_raw, float* __restrict__ sup) {
    __shared__ float a[64][65];
    for (int idx = threadIdx.x; idx < 4096; idx += 64) {
        const float v = am_raw[idx] - 0.5f;
        a[idx >> 6][idx & 63] = v > 0.f ? v : 0.f;
    }
    __syncthreads();
    const int r = threadIdx.x;
    {
        float rs = 0.f;
        for (int j = 0; j < 64; ++j) rs += a[r][j];
        const float dinv = rs > 0.f ? 1.f / rs : 0.f;
        float mx = -1e30f;
        for (int j = 0; j < 64; ++j) mx = fmaxf(mx, a[r][j] * dinv);
        float se = 0.f;
        for (int j = 0; j < 64; ++j) se += expf(a[r][j] * dinv - mx);
        const float inv = 1.f / se;
        for (int j = 0; j < 64; ++j) sup[r * 64 + j] = expf(a[r][j] * dinv - mx) * inv;
    }
    {
        float rs = 0.f;
        for (int j = 0; j < 64; ++j) rs += a[j][r];
        const float dinv = rs > 0.f ? 1.f / rs : 0.f;
        float mx = -1e30f;
        for (int j = 0; j < 64; ++j) mx = fmaxf(mx, a[j][r] * dinv);
        float se = 0.f;
        for (int j = 0; j < 64; ++j) se += expf(a[j][r] * dinv - mx);
        const float inv = 1.f / se;
        for (int j = 0; j < 64; ++j) sup[4096 + r * 64 + j] = expf(a[j][r] * dinv - mx) * inv;
    }
}

// =====================================================================
extern "C" void kernel_launch(void* const* d_in, const int* in_sizes, int n_in,
                              void* d_out, int out_size, void* d_ws, size_t ws_size,
                              hipStream_t stream) {
    (void)in_sizes; (void)n_in; (void)out_size; (void)ws_size;
    const float* x    = (const float*)d_in[0];
    const float* sup  = (const float*)d_in[1];  // [2, V, V]
    const float* supc = (const float*)d_in[2];  // [2, VC, VC]
    const float* acs  = (const float*)d_in[3];  // [VC, S]
    const float* afc  = (const float*)d_in[4];  // [V, VC]
    const float* W    = (const float*)d_in[5];  // [32, 96]
    const float* b    = (const float*)d_in[6];  // [32]
    float* ws = (float*)d_ws;

    // --- region A [0, 12,582,912): xt fp32 (alive steps 1-4); then reused:
    float* xt = ws;
    unsigned short* Btu = (unsigned short*)ws;                // bf16 [2048][4096], from step 5
    float* yc0  = ws + 4456448;
    float* yc12 = ws + 6029312;
    float* ys0  = ws + 9175040;
    float* ys12 = ws + 9568256;
    float* hc   = ws + 10354688;
    float* hs   = ws + 11927552;
    float* am   = ws + 12320768;
    float* sups = ws + 12324864;
    float* acsT = ws + 12333056;                              // ends 12,349,440
    // --- fixed regions
    float* hf   = ws + 12582912;                              // y0 then hf
    float* xc   = ws + 25165824;
    float* sxg  = ws + 26738688;
    unsigned short* afcTb = (unsigned short*)(ws + 27131904); // bf16 [256][2048], whole session
    unsigned short* afcb  = (unsigned short*)(ws + 27394048); // bf16 [2048][256], whole session
    // ws total 27,656,192 floats (~110.6 MB)

    // --- d_out doubles as scratch (dead before final output writes)
    float* out_f = (float*)d_out;
    unsigned short* xtb  = (unsigned short*)d_out;            // bf16 [6144][2048], steps 1-3
    unsigned short* y12u = (unsigned short*)d_out;            // bf16 [6144][4096], steps 4-11
    unsigned short* hfb  = (unsigned short*)d_out;            // bf16 [6144][2048], steps 15-19
    unsigned short* hcb  = ((unsigned short*)d_out) + 12582912;  // bf16 [6144][256]
    float* hf_out = out_f;
    float* hc_out = out_f + 12582912;
    float* hs_out = out_f + 14155776;

    // 1. xt = transpose(x) (+ bf16 copy xtb into d_out)
    transpose_vl<<<dim3(VV / 128, NB * CC), 256, 0, stream>>>(x, xt, xtb);
    // 2. afcb + afcTb in one pass (ws tail - no conflict with live xt)
    cvt_afc_both<<<dim3(VCC / 32, VV / 32), 256, 0, stream>>>(afc, afcb, afcTb);
    // 3. xc = xtb @ afc  (MFMA BN=64; B^T = afcTb)  grid (4,48)=192 blocks
    gemm_mfma<64, false, false, false, false, false><<<dim3(VCC / 64, MM / 128), 256, 0, stream>>>(
        xtb, VV, afcTb, VV, nullptr, 0, nullptr, xc, VCC, nullptr, VV, 1.0f);
    // 4. fine chanmix: y0 -> hf (fp32), y12 -> d_out (bf16; clobbers xtb - dead)
    chanmix_fine<<<dim3(96, 16), 256, 0, stream>>>(xt, W, hf, y12u);
    // 5. Btu = bf16([A1;A2]^T) [2048][4096]  (region A; xt dead after step 4)
    cvt_T_bf16_k<<<dim3(VV / 32, 2 * VV / 32), 256, 0, stream>>>(sup, Btu, 2 * VV, VV);
    // 6. sxg = xc @ acs (fp32)
    gemm_k<64, 64, 16, 4, 4, false, false, false, false><<<dim3(1, MM / 64), 256, 0, stream>>>(
        xc, VCC, acs, SS, nullptr, 0, nullptr, sxg, SS, nullptr, VCC, 1.0f);
    // 7. coarse chanmix
    chanmix_k<<<dim3(12, 16), 256, 0, stream>>>(xc, W, LL * VCC, VCC, yc0, yc12, 2 * VCC);
    // 8. super chanmix
    chanmix_k<<<dim3(3, 16), 256, 0, stream>>>(sxg, W, LL * SS, SS, ys0, ys12, 2 * SS);
    // 9. gram + supports
    zero_k<<<dim3(4), 256, 0, stream>>>(am, 4096);
    asmat_split<<<dim3(48), 256, 0, stream>>>(sxg, am);
    supbuild_k<<<dim3(1), 64, 0, stream>>>(am, sups);
    // 10. K3 (MFMA, fused supports, GROUP_M=8 swizzle): hf = y0 + y12 @ [A1;A2] + bias
    gemm_mfma<128, true, false, true, true, false><<<dim3(VV / 128, MM / 128), 256, 0, stream>>>(
        y12u, 4096, Btu, 4096, hf, VV, b, hf, VV, nullptr, 4096, 1.0f);
    // 11. hc = yc0 + yc12 @ [Ac1;Ac2] + bias (fp32)
    gemm_k<64, 64, 16, 4, 4, false, true, true, false><<<dim3(VCC / 64, MM / 64), 256, 0, stream>>>(
        yc12, 2 * VCC, supc, VCC, yc0, VCC, b, hc, VCC, nullptr, 2 * VCC, 1.0f);
    // 12. hs = ys0 + ys12 @ [As1;As2] + bias (fp32)
    gemm_k<64, 64, 16, 4, 4, false, true, true, false><<<dim3(1, MM / 64), 256, 0, stream>>>(
        ys12, 2 * SS, sups, SS, ys0, SS, b, hs, SS, nullptr, 2 * SS, 1.0f);
    // 13. acsT (fp32)
    transpose2d<<<dim3(SS / 32, VCC / 32), 256, 0, stream>>>(acs, acsT, VCC, SS);
    // 14. hc += 0.8 * relu(hs @ acs^T), dual-store hcb bf16 (y12u dead)
    gemm_k<64, 64, 16, 4, 4, true, true, false, true><<<dim3(VCC / 64, MM / 64), 256, 0, stream>>>(
        hs, SS, acsT, VCC, hc, VCC, nullptr, hc, VCC, hcb, SS, 0.8f);
    // 15. hf += 0.2 * relu(hcb @ afc^T) (MFMA, swizzle), dual-store hfb bf16
    gemm_mfma<128, true, true, true, false, true><<<dim3(VV / 128, MM / 128), 256, 0, stream>>>(
        hcb, VCC, afcb, VCC, hf, VV, nullptr, hf, VV, hfb, VCC, 0.2f);
    // 16. hc += 0.2 * relu(hfb @ afc) (MFMA BN=64; B^T = afcTb)
    gemm_mfma<64, false, true, true, false, false><<<dim3(VCC / 64, MM / 128), 256, 0, stream>>>(
        hfb, VV, afcTb, VV, hc, VCC, nullptr, hc, VCC, nullptr, VV, 0.2f);
    // 17. hs += 0.2 * relu(hc @ acs) (fp32, K=256)
    gemm_k<64, 64, 16, 4, 4, true, true, false, false><<<dim3(1, MM / 64), 256, 0, stream>>>(
        hc, VCC, acs, SS, hs, SS, nullptr, hs, SS, nullptr, VCC, 0.2f);
    // 18. node-last -> reference layout [*, node, L]
    transpose_lv<<<dim3(VV / 128, NB * CO), 256, 0, stream>>>(hf, hf_out, VV, 128);
    transpose_lv<<<dim3(VCC / 128, NB * CO), 256, 0, stream>>>(hc, hc_out, VCC, 128);
    transpose_lv<<<dim3(1, NB * CO), 256, 0, stream>>>(hs, hs_out, SS, 64);
}